// Round 1
// baseline (1227.806 us; speedup 1.0000x reference)
//
#include <hip/hip_runtime.h>
#include <hip/hip_bf16.h>
#include <math.h>

// Problem constants
#define BB 8
#define TT 2048
#define HH 1024
#define FF 4096
#define EE 8

typedef __attribute__((ext_vector_type(8))) short sh8;   // 8 bf16 (4 VGPRs)
typedef __attribute__((ext_vector_type(4))) float f32x4; // MFMA acc
typedef __attribute__((ext_vector_type(4))) float f4;

__device__ inline unsigned short f2bf(float f) {
  unsigned u = __builtin_bit_cast(unsigned, f);
  u += 0x7FFFu + ((u >> 16) & 1u);
  return (unsigned short)(u >> 16);
}

// ---------------- X f32 -> bf16 ----------------
__global__ __launch_bounds__(256) void convert_x(const float* __restrict__ X,
                                                 unsigned short* __restrict__ Xb) {
  size_t i = ((size_t)blockIdx.x * 256 + threadIdx.x) * 8;
  f4 v0 = *(const f4*)&X[i];
  f4 v1 = *(const f4*)&X[i + 4];
  sh8 o;
  o[0] = (short)f2bf(v0[0]); o[1] = (short)f2bf(v0[1]);
  o[2] = (short)f2bf(v0[2]); o[3] = (short)f2bf(v0[3]);
  o[4] = (short)f2bf(v1[0]); o[5] = (short)f2bf(v1[1]);
  o[6] = (short)f2bf(v1[2]); o[7] = (short)f2bf(v1[3]);
  *(sh8*)&Xb[i] = o;
}

// ---------------- mean over T, partial sums ----------------
__global__ __launch_bounds__(256) void mean_partial(const float* __restrict__ X,
                                                    float* __restrict__ partial) {
  int tc = blockIdx.x, b = blockIdx.y, t = threadIdx.x;
  float s0 = 0.f, s1 = 0.f, s2 = 0.f, s3 = 0.f;
  const float* base = X + (size_t)b * TT * HH + (size_t)tc * 128 * HH;
  for (int tt = 0; tt < 128; tt++) {
    const float* r = base + (size_t)tt * HH;
    s0 += r[t];
    s1 += r[t + 256];
    s2 += r[t + 512];
    s3 += r[t + 768];
  }
  float* o = partial + ((size_t)b * 16 + tc) * HH;
  o[t] = s0; o[t + 256] = s1; o[t + 512] = s2; o[t + 768] = s3;
}

// ---------------- gating: logits -> softmax -> top2 -> routing ----------------
__global__ __launch_bounds__(256) void gating_kernel(const float* __restrict__ partial,
                                                     const float* __restrict__ gw,
                                                     int* __restrict__ re,
                                                     float* __restrict__ rw) {
  int b = blockIdx.x, t = threadIdx.x;
  float acc[EE];
#pragma unroll
  for (int e = 0; e < EE; e++) acc[e] = 0.f;
  for (int jj = 0; jj < 4; jj++) {
    int h = t + jj * 256;
    float s = 0.f;
    for (int tc = 0; tc < 16; tc++) s += partial[((size_t)b * 16 + tc) * HH + h];
    s *= (1.0f / (float)TT);
#pragma unroll
    for (int e = 0; e < EE; e++) acc[e] += s * gw[h * EE + e];
  }
#pragma unroll
  for (int off = 32; off >= 1; off >>= 1) {
#pragma unroll
    for (int e = 0; e < EE; e++) acc[e] += __shfl_down(acc[e], off);
  }
  __shared__ float red[4][EE];
  if ((t & 63) == 0) {
#pragma unroll
    for (int e = 0; e < EE; e++) red[t >> 6][e] = acc[e];
  }
  __syncthreads();
  if (t == 0) {
    float lg[EE];
#pragma unroll
    for (int e = 0; e < EE; e++) lg[e] = red[0][e] + red[1][e] + red[2][e] + red[3][e];
    float mx = lg[0];
#pragma unroll
    for (int e = 1; e < EE; e++) mx = fmaxf(mx, lg[e]);
    float p[EE]; float s = 0.f;
#pragma unroll
    for (int e = 0; e < EE; e++) { p[e] = expf(lg[e] - mx); s += p[e]; }
#pragma unroll
    for (int e = 0; e < EE; e++) p[e] /= s;
    int i1 = 0;
#pragma unroll
    for (int e = 1; e < EE; e++) if (p[e] > p[i1]) i1 = e;  // first index wins ties
    int i2 = -1;
#pragma unroll
    for (int e = 0; e < EE; e++) {
      if (e == i1) continue;
      if (i2 < 0 || p[e] > p[i2]) i2 = e;
    }
    float den = p[i1] + p[i2];
    re[b * 2 + 0] = i1; rw[b * 2 + 0] = p[i1] / den;
    re[b * 2 + 1] = i2; rw[b * 2 + 1] = p[i2] / den;
  }
}

// ---------------- transpose+convert weights into tiled bf16 [K/32][N/128][128][32] ----------------
// in: W[e][K][N] f32 row-major; out slot z: n-major-k-contig tiles.
__global__ __launch_bounds__(256) void transposeK(const float* __restrict__ W,
                                                  unsigned short* __restrict__ Wt,
                                                  const int* __restrict__ re, int rb,
                                                  int K, int N) {
  __shared__ float tile[32][132];
  int kb = blockIdx.x, nb = blockIdx.y, z = blockIdx.z;
  int e = re[rb + z];
  const float* src = W + (size_t)e * K * N;
  unsigned short* dst = Wt + (size_t)z * K * N +
                        ((size_t)kb * (N / 128) + nb) * 4096;
  int t = threadIdx.x;
#pragma unroll
  for (int pass = 0; pass < 4; pass++) {
    int g = t + pass * 256;
    int r = g >> 5, cq = (g & 31) * 4;
    f4 v = *(const f4*)&src[(size_t)(kb * 32 + r) * N + nb * 128 + cq];
    *(f4*)&tile[r][cq] = v;
  }
  __syncthreads();
#pragma unroll
  for (int pass = 0; pass < 2; pass++) {
    int idx = (t + pass * 256) * 8;
    int nl = idx >> 5, k0 = idx & 31;
    sh8 o;
#pragma unroll
    for (int j = 0; j < 8; j++) o[j] = (short)f2bf(tile[k0 + j][nl]);
    *(sh8*)&dst[idx] = o;
  }
}

// ---------------- GEMM1: hmid[slot] = gelu(X[b] @ w1[e] + b1[e]) in bf16 ----------------
__global__ __launch_bounds__(256) void gemm1(const unsigned short* __restrict__ Xbf,
                                             const unsigned short* __restrict__ w1t,
                                             const float* __restrict__ pb1,
                                             const int* __restrict__ re,
                                             unsigned short* __restrict__ hmid,
                                             int rb) {
  int nb = blockIdx.x, mb = blockIdx.y, z = blockIdx.z;
  int p = rb + z;
  int b = p >> 1;
  int e = re[p];
  const unsigned short* A = Xbf + (size_t)b * TT * HH + (size_t)mb * 128 * HH;
  const unsigned short* Bt = w1t + (size_t)z * HH * FF;
  unsigned short* Cout = hmid + (size_t)z * TT * FF;

  __shared__ unsigned short Al[2][4096];
  __shared__ unsigned short Bl[2][4096];

  int t = threadIdx.x;
  int lane = t & 63, wv = t >> 6;
  int wr = wv >> 1, wc = wv & 1;
  int ln = lane & 15, kq = lane >> 4;

  const int NK = HH / 32;

  f32x4 zero = {0.f, 0.f, 0.f, 0.f};
  f32x4 acc[4][4];
#pragma unroll
  for (int m = 0; m < 4; m++)
#pragma unroll
    for (int n = 0; n < 4; n++) acc[m][n] = zero;

  // prologue: stage tile 0
  {
    int g0 = t, g1 = t + 256;
    sh8 a0 = *(const sh8*)&A[(size_t)(g0 >> 2) * HH + (g0 & 3) * 8];
    sh8 a1 = *(const sh8*)&A[(size_t)(g1 >> 2) * HH + (g1 & 3) * 8];
    const unsigned short* tb = Bt + ((size_t)0 * (FF / 128) + nb) * 4096;
    sh8 b0 = *(const sh8*)&tb[t * 8];
    sh8 bx = *(const sh8*)&tb[t * 8 + 2048];
    *(sh8*)&Al[0][t * 8] = a0;
    *(sh8*)&Al[0][t * 8 + 2048] = a1;
    *(sh8*)&Bl[0][t * 8] = b0;
    *(sh8*)&Bl[0][t * 8 + 2048] = bx;
  }
  int cur = 0;
  for (int ks = 0; ks < NK; ks++) {
    __syncthreads();
    bool pre = (ks + 1 < NK);
    sh8 nA0, nA1, nB0, nB1;
    if (pre) {
      int g0 = t, g1 = t + 256;
      nA0 = *(const sh8*)&A[(size_t)(g0 >> 2) * HH + (ks + 1) * 32 + (g0 & 3) * 8];
      nA1 = *(const sh8*)&A[(size_t)(g1 >> 2) * HH + (ks + 1) * 32 + (g1 & 3) * 8];
      const unsigned short* tb = Bt + ((size_t)(ks + 1) * (FF / 128) + nb) * 4096;
      nB0 = *(const sh8*)&tb[t * 8];
      nB1 = *(const sh8*)&tb[t * 8 + 2048];
    }
    sh8 af[4], bf[4];
#pragma unroll
    for (int m = 0; m < 4; m++)
      af[m] = *(const sh8*)&Al[cur][(wr * 64 + m * 16 + ln) * 32 + kq * 8];
#pragma unroll
    for (int n = 0; n < 4; n++)
      bf[n] = *(const sh8*)&Bl[cur][(wc * 64 + n * 16 + ln) * 32 + kq * 8];
#pragma unroll
    for (int m = 0; m < 4; m++)
#pragma unroll
      for (int n = 0; n < 4; n++)
        acc[m][n] = __builtin_amdgcn_mfma_f32_16x16x32_bf16(af[m], bf[n], acc[m][n], 0, 0, 0);
    if (pre) {
      *(sh8*)&Al[cur ^ 1][t * 8] = nA0;
      *(sh8*)&Al[cur ^ 1][t * 8 + 2048] = nA1;
      *(sh8*)&Bl[cur ^ 1][t * 8] = nB0;
      *(sh8*)&Bl[cur ^ 1][t * 8 + 2048] = nB1;
      cur ^= 1;
    }
  }

  int col0 = nb * 128 + wc * 64;
  int row0 = mb * 128 + wr * 64;
  float bbv[4];
#pragma unroll
  for (int n = 0; n < 4; n++) bbv[n] = pb1[(size_t)e * FF + col0 + n * 16 + ln];
#pragma unroll
  for (int m = 0; m < 4; m++) {
#pragma unroll
    for (int n = 0; n < 4; n++) {
#pragma unroll
      for (int j = 0; j < 4; j++) {
        int row = row0 + m * 16 + kq * 4 + j;
        int col = col0 + n * 16 + ln;
        float v = acc[m][n][j] + bbv[n];
        float g = 0.5f * v * (1.0f + erff(v * 0.70710678118654752f));
        Cout[(size_t)row * FF + col] = f2bf(g);
      }
    }
  }
}

// ---------------- GEMM2: out[b] (=/+=) wgt*(hmid @ w2[e] + b2[e]) ----------------
__global__ __launch_bounds__(256) void gemm2(const unsigned short* __restrict__ hmid,
                                             const unsigned short* __restrict__ w2t,
                                             const float* __restrict__ pb2,
                                             const int* __restrict__ re,
                                             const float* __restrict__ rw,
                                             float* __restrict__ out,
                                             int rb, int first) {
  int nb = blockIdx.x, mb = blockIdx.y;
  int p = first + 2 * blockIdx.z;
  int slot = p - rb;
  int b = p >> 1;
  int e = re[p];
  float wgt = rw[p];
  int accum = p & 1;

  const unsigned short* A = hmid + (size_t)slot * TT * FF + (size_t)mb * 128 * FF;
  const unsigned short* Bt = w2t + (size_t)slot * FF * HH;

  __shared__ unsigned short Al[2][4096];
  __shared__ unsigned short Bl[2][4096];

  int t = threadIdx.x;
  int lane = t & 63, wv = t >> 6;
  int wr = wv >> 1, wc = wv & 1;
  int ln = lane & 15, kq = lane >> 4;

  const int NK = FF / 32;

  f32x4 zero = {0.f, 0.f, 0.f, 0.f};
  f32x4 acc[4][4];
#pragma unroll
  for (int m = 0; m < 4; m++)
#pragma unroll
    for (int n = 0; n < 4; n++) acc[m][n] = zero;

  {
    int g0 = t, g1 = t + 256;
    sh8 a0 = *(const sh8*)&A[(size_t)(g0 >> 2) * FF + (g0 & 3) * 8];
    sh8 a1 = *(const sh8*)&A[(size_t)(g1 >> 2) * FF + (g1 & 3) * 8];
    const unsigned short* tb = Bt + ((size_t)0 * (HH / 128) + nb) * 4096;
    sh8 b0 = *(const sh8*)&tb[t * 8];
    sh8 bx = *(const sh8*)&tb[t * 8 + 2048];
    *(sh8*)&Al[0][t * 8] = a0;
    *(sh8*)&Al[0][t * 8 + 2048] = a1;
    *(sh8*)&Bl[0][t * 8] = b0;
    *(sh8*)&Bl[0][t * 8 + 2048] = bx;
  }
  int cur = 0;
  for (int ks = 0; ks < NK; ks++) {
    __syncthreads();
    bool pre = (ks + 1 < NK);
    sh8 nA0, nA1, nB0, nB1;
    if (pre) {
      int g0 = t, g1 = t + 256;
      nA0 = *(const sh8*)&A[(size_t)(g0 >> 2) * FF + (ks + 1) * 32 + (g0 & 3) * 8];
      nA1 = *(const sh8*)&A[(size_t)(g1 >> 2) * FF + (ks + 1) * 32 + (g1 & 3) * 8];
      const unsigned short* tb = Bt + ((size_t)(ks + 1) * (HH / 128) + nb) * 4096;
      nB0 = *(const sh8*)&tb[t * 8];
      nB1 = *(const sh8*)&tb[t * 8 + 2048];
    }
    sh8 af[4], bf[4];
#pragma unroll
    for (int m = 0; m < 4; m++)
      af[m] = *(const sh8*)&Al[cur][(wr * 64 + m * 16 + ln) * 32 + kq * 8];
#pragma unroll
    for (int n = 0; n < 4; n++)
      bf[n] = *(const sh8*)&Bl[cur][(wc * 64 + n * 16 + ln) * 32 + kq * 8];
#pragma unroll
    for (int m = 0; m < 4; m++)
#pragma unroll
      for (int n = 0; n < 4; n++)
        acc[m][n] = __builtin_amdgcn_mfma_f32_16x16x32_bf16(af[m], bf[n], acc[m][n], 0, 0, 0);
    if (pre) {
      *(sh8*)&Al[cur ^ 1][t * 8] = nA0;
      *(sh8*)&Al[cur ^ 1][t * 8 + 2048] = nA1;
      *(sh8*)&Bl[cur ^ 1][t * 8] = nB0;
      *(sh8*)&Bl[cur ^ 1][t * 8 + 2048] = nB1;
      cur ^= 1;
    }
  }

  int col0 = nb * 128 + wc * 64;
  int row0 = mb * 128 + wr * 64;
  float bbv[4];
#pragma unroll
  for (int n = 0; n < 4; n++) bbv[n] = pb2[(size_t)e * HH + col0 + n * 16 + ln];
#pragma unroll
  for (int m = 0; m < 4; m++) {
#pragma unroll
    for (int n = 0; n < 4; n++) {
#pragma unroll
      for (int j = 0; j < 4; j++) {
        int row = row0 + m * 16 + kq * 4 + j;
        int col = col0 + n * 16 + ln;
        float v = wgt * (acc[m][n][j] + bbv[n]);
        size_t oi = (size_t)b * TT * HH + (size_t)row * HH + col;
        if (accum) out[oi] = out[oi] + v;
        else out[oi] = v;
      }
    }
  }
}

extern "C" void kernel_launch(void* const* d_in, const int* in_sizes, int n_in,
                              void* d_out, int out_size, void* d_ws, size_t ws_size,
                              hipStream_t stream) {
  const float* X  = (const float*)d_in[0];
  const float* gw = (const float*)d_in[1];
  const float* w1 = (const float*)d_in[2];
  const float* pb1 = (const float*)d_in[3];
  const float* w2 = (const float*)d_in[4];
  const float* pb2 = (const float*)d_in[5];
  float* out = (float*)d_out;

  char* ws = (char*)d_ws;
  int* re = (int*)ws;                     // 16 ints: routed expert per pair
  float* rw = (float*)(ws + 64);          // 16 floats: normalized weight per pair
  float* partial = (float*)(ws + 256);    // [B][16][H] f32 = 512KB
  unsigned short* Xbf = (unsigned short*)(ws + 256 + 524288);  // [B][T][H] bf16
  const size_t fixed = 256 + 524288 + (size_t)BB * TT * HH * 2;  // 34,078,976
  char* dyn = ws + fixed;

  const size_t w1t_slot = (size_t)HH * FF * 2;   // 8,388,608
  const size_t w2t_slot = (size_t)FF * HH * 2;   // 8,388,608
  const size_t hmid_slot = (size_t)TT * FF * 2;  // 16,777,216
  const size_t per_pair = w1t_slot + w2t_slot + hmid_slot;

  int G = 1;
  if (ws_size > fixed + per_pair) {
    size_t g = (ws_size - fixed) / per_pair;
    G = (int)(g < 16 ? g : 16);
  }
  unsigned short* w1t = (unsigned short*)dyn;
  unsigned short* w2t = (unsigned short*)(dyn + (size_t)G * w1t_slot);
  unsigned short* hmid = (unsigned short*)(dyn + (size_t)G * (w1t_slot + w2t_slot));

  convert_x<<<8192, 256, 0, stream>>>(X, Xbf);
  mean_partial<<<dim3(16, BB), 256, 0, stream>>>(X, partial);
  gating_kernel<<<BB, 256, 0, stream>>>(partial, gw, re, rw);

  for (int rb = 0; rb < 16; rb += G) {
    int Gr = (16 - rb < G) ? (16 - rb) : G;
    transposeK<<<dim3(HH / 32, FF / 128, Gr), 256, 0, stream>>>(w1, w1t, re, rb, HH, FF);
    transposeK<<<dim3(FF / 32, HH / 128, Gr), 256, 0, stream>>>(w2, w2t, re, rb, FF, HH);
    gemm1<<<dim3(FF / 128, TT / 128, Gr), 256, 0, stream>>>(Xbf, w1t, pb1, re, hmid, rb);
    for (int par = 0; par < 2; par++) {
      int first = rb + ((par - rb) & 1);
      int last = rb + Gr - 1;
      if (first > last) continue;
      int cnt = (last - first) / 2 + 1;
      gemm2<<<dim3(HH / 128, TT / 128, cnt), 256, 0, stream>>>(hmid, w2t, pb2, re, rw, out, rb, first);
    }
  }
}

// Round 2
// 1114.705 us; speedup vs baseline: 1.1015x; 1.1015x over previous
//
#include <hip/hip_runtime.h>
#include <hip/hip_bf16.h>
#include <math.h>

// Problem constants
#define BB 8
#define TT 2048
#define HH 1024
#define FF 4096
#define EE 8

typedef __attribute__((ext_vector_type(8))) short sh8;   // 8 bf16 (4 VGPRs)
typedef __attribute__((ext_vector_type(4))) float f32x4; // MFMA acc
typedef __attribute__((ext_vector_type(4))) float f4;

__device__ inline unsigned short f2bf(float f) {
  unsigned u = __builtin_bit_cast(unsigned, f);
  u += 0x7FFFu + ((u >> 16) & 1u);
  return (unsigned short)(u >> 16);
}

// async global->LDS, 16B per lane, wave-uniform LDS base + lane*16
__device__ inline void gload_lds16(const void* g, void* l) {
  __builtin_amdgcn_global_load_lds(
      (const __attribute__((address_space(1))) unsigned int*)g,
      (__attribute__((address_space(3))) unsigned int*)l, 16, 0, 0);
}

// ---------------- X f32 -> bf16 ----------------
__global__ __launch_bounds__(256) void convert_x(const float* __restrict__ X,
                                                 unsigned short* __restrict__ Xb) {
  size_t i = ((size_t)blockIdx.x * 256 + threadIdx.x) * 8;
  f4 v0 = *(const f4*)&X[i];
  f4 v1 = *(const f4*)&X[i + 4];
  sh8 o;
  o[0] = (short)f2bf(v0[0]); o[1] = (short)f2bf(v0[1]);
  o[2] = (short)f2bf(v0[2]); o[3] = (short)f2bf(v0[3]);
  o[4] = (short)f2bf(v1[0]); o[5] = (short)f2bf(v1[1]);
  o[6] = (short)f2bf(v1[2]); o[7] = (short)f2bf(v1[3]);
  *(sh8*)&Xb[i] = o;
}

// ---------------- mean over T, partial sums ----------------
__global__ __launch_bounds__(256) void mean_partial(const float* __restrict__ X,
                                                    float* __restrict__ partial) {
  int tc = blockIdx.x, b = blockIdx.y, t = threadIdx.x;
  float s0 = 0.f, s1 = 0.f, s2 = 0.f, s3 = 0.f;
  const float* base = X + (size_t)b * TT * HH + (size_t)tc * 128 * HH;
  for (int tt = 0; tt < 128; tt++) {
    const float* r = base + (size_t)tt * HH;
    s0 += r[t];
    s1 += r[t + 256];
    s2 += r[t + 512];
    s3 += r[t + 768];
  }
  float* o = partial + ((size_t)b * 16 + tc) * HH;
  o[t] = s0; o[t + 256] = s1; o[t + 512] = s2; o[t + 768] = s3;
}

// ---------------- gating: logits -> softmax -> top2 -> routing ----------------
__global__ __launch_bounds__(256) void gating_kernel(const float* __restrict__ partial,
                                                     const float* __restrict__ gw,
                                                     int* __restrict__ re,
                                                     float* __restrict__ rw) {
  int b = blockIdx.x, t = threadIdx.x;
  float acc[EE];
#pragma unroll
  for (int e = 0; e < EE; e++) acc[e] = 0.f;
  for (int jj = 0; jj < 4; jj++) {
    int h = t + jj * 256;
    float s = 0.f;
    for (int tc = 0; tc < 16; tc++) s += partial[((size_t)b * 16 + tc) * HH + h];
    s *= (1.0f / (float)TT);
#pragma unroll
    for (int e = 0; e < EE; e++) acc[e] += s * gw[h * EE + e];
  }
#pragma unroll
  for (int off = 32; off >= 1; off >>= 1) {
#pragma unroll
    for (int e = 0; e < EE; e++) acc[e] += __shfl_down(acc[e], off);
  }
  __shared__ float red[4][EE];
  if ((t & 63) == 0) {
#pragma unroll
    for (int e = 0; e < EE; e++) red[t >> 6][e] = acc[e];
  }
  __syncthreads();
  if (t == 0) {
    float lg[EE];
#pragma unroll
    for (int e = 0; e < EE; e++) lg[e] = red[0][e] + red[1][e] + red[2][e] + red[3][e];
    float mx = lg[0];
#pragma unroll
    for (int e = 1; e < EE; e++) mx = fmaxf(mx, lg[e]);
    float p[EE]; float s = 0.f;
#pragma unroll
    for (int e = 0; e < EE; e++) { p[e] = expf(lg[e] - mx); s += p[e]; }
#pragma unroll
    for (int e = 0; e < EE; e++) p[e] /= s;
    int i1 = 0;
#pragma unroll
    for (int e = 1; e < EE; e++) if (p[e] > p[i1]) i1 = e;  // first index wins ties
    int i2 = -1;
#pragma unroll
    for (int e = 0; e < EE; e++) {
      if (e == i1) continue;
      if (i2 < 0 || p[e] > p[i2]) i2 = e;
    }
    float den = p[i1] + p[i2];
    re[b * 2 + 0] = i1; rw[b * 2 + 0] = p[i1] / den;
    re[b * 2 + 1] = i2; rw[b * 2 + 1] = p[i2] / den;
  }
}

// ---------------- transpose+convert per-EXPERT weights into tiled bf16 ----------------
// in: W[e][K][N] f32 row-major; out per-expert slot e: [K/32][N/128] tiles of
// [128 n-local][32 k-local] bf16 (k-contig). Blocks for unused experts exit early.
__global__ __launch_bounds__(256) void transposeE(const float* __restrict__ W,
                                                  unsigned short* __restrict__ Wt,
                                                  const int* __restrict__ re,
                                                  int K, int N) {
  int e = blockIdx.z;
  bool u = false;
#pragma unroll
  for (int p = 0; p < 16; p++) u = u || (re[p] == e);
  if (!u) return;

  __shared__ float tile[32][132];
  int kb = blockIdx.x, nb = blockIdx.y;
  const float* src = W + (size_t)e * K * N;
  unsigned short* dst = Wt + (size_t)e * K * N +
                        ((size_t)kb * (N / 128) + nb) * 4096;
  int t = threadIdx.x;
#pragma unroll
  for (int pass = 0; pass < 4; pass++) {
    int g = t + pass * 256;
    int r = g >> 5, cq = (g & 31) * 4;
    f4 v = *(const f4*)&src[(size_t)(kb * 32 + r) * N + nb * 128 + cq];
    *(f4*)&tile[r][cq] = v;
  }
  __syncthreads();
#pragma unroll
  for (int pass = 0; pass < 2; pass++) {
    int idx = (t + pass * 256) * 8;
    int nl = idx >> 5, k0 = idx & 31;
    sh8 o;
#pragma unroll
    for (int j = 0; j < 8; j++) o[j] = (short)f2bf(tile[k0 + j][nl]);
    *(sh8*)&dst[idx] = o;
  }
}

// ---------------- GEMM1: hmid[p] = rw[p] * gelu(X[b] @ w1[e] + b1[e]) in bf16 ----------------
__global__ __launch_bounds__(256) void gemm1(const unsigned short* __restrict__ Xbf,
                                             const unsigned short* __restrict__ w1t,
                                             const float* __restrict__ pb1,
                                             const int* __restrict__ re,
                                             const float* __restrict__ rw,
                                             unsigned short* __restrict__ hmid) {
  int nb = blockIdx.x, mb = blockIdx.y, p = blockIdx.z;
  int b = p >> 1;
  int e = re[p];
  float wgt = rw[p];
  const unsigned short* A = Xbf + (size_t)b * TT * HH + (size_t)mb * 128 * HH;
  const unsigned short* Bt = w1t + (size_t)e * HH * FF;
  unsigned short* Cout = hmid + (size_t)p * TT * FF;

  __shared__ unsigned short Al[2][4096];
  __shared__ unsigned short Bl[2][4096];

  int t = threadIdx.x;
  int lane = t & 63, wv = t >> 6;
  int wr = wv >> 1, wc = wv & 1;
  int ln = lane & 15, kq = lane >> 4;

  const int NK = HH / 32;

  f32x4 zero = {0.f, 0.f, 0.f, 0.f};
  f32x4 acc[4][4];
#pragma unroll
  for (int m = 0; m < 4; m++)
#pragma unroll
    for (int n = 0; n < 4; n++) acc[m][n] = zero;

#define STAGE1(buf, ks) do {                                                       \
    int g0 = t, g1 = t + 256;                                                      \
    gload_lds16(&A[(size_t)(g0 >> 2) * HH + (ks) * 32 + (g0 & 3) * 8],             \
                &Al[buf][g0 * 8]);                                                 \
    gload_lds16(&A[(size_t)(g1 >> 2) * HH + (ks) * 32 + (g1 & 3) * 8],             \
                &Al[buf][g1 * 8]);                                                 \
    const unsigned short* tb = Bt + ((size_t)(ks) * (FF / 128) + nb) * 4096;       \
    gload_lds16(&tb[g0 * 8], &Bl[buf][g0 * 8]);                                    \
    gload_lds16(&tb[g1 * 8], &Bl[buf][g1 * 8]);                                    \
  } while (0)

  STAGE1(0, 0);
  int cur = 0;
  for (int ks = 0; ks < NK; ks++) {
    __syncthreads();   // drains vmcnt -> staged tile `cur` ready; prev reads done
    if (ks + 1 < NK) STAGE1(cur ^ 1, ks + 1);
    sh8 af[4], bfr[4];
#pragma unroll
    for (int m = 0; m < 4; m++)
      af[m] = *(const sh8*)&Al[cur][(wr * 64 + m * 16 + ln) * 32 + kq * 8];
#pragma unroll
    for (int n = 0; n < 4; n++)
      bfr[n] = *(const sh8*)&Bl[cur][(wc * 64 + n * 16 + ln) * 32 + kq * 8];
#pragma unroll
    for (int m = 0; m < 4; m++)
#pragma unroll
      for (int n = 0; n < 4; n++)
        acc[m][n] = __builtin_amdgcn_mfma_f32_16x16x32_bf16(af[m], bfr[n], acc[m][n], 0, 0, 0);
    cur ^= 1;
  }
#undef STAGE1

  int col0 = nb * 128 + wc * 64;
  int row0 = mb * 128 + wr * 64;
  float bbv[4];
#pragma unroll
  for (int n = 0; n < 4; n++) bbv[n] = pb1[(size_t)e * FF + col0 + n * 16 + ln];
#pragma unroll
  for (int m = 0; m < 4; m++) {
#pragma unroll
    for (int n = 0; n < 4; n++) {
#pragma unroll
      for (int j = 0; j < 4; j++) {
        int row = row0 + m * 16 + kq * 4 + j;
        int col = col0 + n * 16 + ln;
        float v = acc[m][n][j] + bbv[n];
        float g = 0.5f * v * (1.0f + erff(v * 0.70710678118654752f));
        Cout[(size_t)row * FF + col] = f2bf(wgt * g);
      }
    }
  }
}

// ---------------- GEMM2: out[b] = (hmid[2b]|hmid[2b+1]) @ (w2[e0];w2[e1]) + weighted bias
// K-concatenated over both experts of the batch; weights already folded into hmid.
__global__ __launch_bounds__(256) void gemm2(const unsigned short* __restrict__ hmid,
                                             const unsigned short* __restrict__ w2t,
                                             const float* __restrict__ pb2,
                                             const int* __restrict__ re,
                                             const float* __restrict__ rw,
                                             float* __restrict__ out) {
  int nb = blockIdx.x, mb = blockIdx.y, b = blockIdx.z;
  int e0 = re[2 * b], e1 = re[2 * b + 1];
  float w0 = rw[2 * b], w1r = rw[2 * b + 1];
  const unsigned short* A0 = hmid + (size_t)(2 * b) * TT * FF + (size_t)mb * 128 * FF;
  const unsigned short* A1 = A0 + (size_t)TT * FF;
  const unsigned short* Bt0 = w2t + (size_t)e0 * FF * HH;
  const unsigned short* Bt1 = w2t + (size_t)e1 * FF * HH;

  __shared__ unsigned short Al[2][4096];
  __shared__ unsigned short Bl[2][4096];

  int t = threadIdx.x;
  int lane = t & 63, wv = t >> 6;
  int wr = wv >> 1, wc = wv & 1;
  int ln = lane & 15, kq = lane >> 4;

  const int NK = 2 * (FF / 32);  // 256 concatenated K-steps

  f32x4 zero = {0.f, 0.f, 0.f, 0.f};
  f32x4 acc[4][4];
#pragma unroll
  for (int m = 0; m < 4; m++)
#pragma unroll
    for (int n = 0; n < 4; n++) acc[m][n] = zero;

#define STAGE2(buf, ks) do {                                                       \
    int kk = (ks) & 127;                                                           \
    const unsigned short* Ax = ((ks) < 128) ? A0 : A1;                             \
    const unsigned short* Bx = ((ks) < 128) ? Bt0 : Bt1;                           \
    int g0 = t, g1 = t + 256;                                                      \
    gload_lds16(&Ax[(size_t)(g0 >> 2) * FF + kk * 32 + (g0 & 3) * 8],              \
                &Al[buf][g0 * 8]);                                                 \
    gload_lds16(&Ax[(size_t)(g1 >> 2) * FF + kk * 32 + (g1 & 3) * 8],              \
                &Al[buf][g1 * 8]);                                                 \
    const unsigned short* tb = Bx + ((size_t)kk * (HH / 128) + nb) * 4096;         \
    gload_lds16(&tb[g0 * 8], &Bl[buf][g0 * 8]);                                    \
    gload_lds16(&tb[g1 * 8], &Bl[buf][g1 * 8]);                                    \
  } while (0)

  STAGE2(0, 0);
  int cur = 0;
  for (int ks = 0; ks < NK; ks++) {
    __syncthreads();
    if (ks + 1 < NK) STAGE2(cur ^ 1, ks + 1);
    sh8 af[4], bfr[4];
#pragma unroll
    for (int m = 0; m < 4; m++)
      af[m] = *(const sh8*)&Al[cur][(wr * 64 + m * 16 + ln) * 32 + kq * 8];
#pragma unroll
    for (int n = 0; n < 4; n++)
      bfr[n] = *(const sh8*)&Bl[cur][(wc * 64 + n * 16 + ln) * 32 + kq * 8];
#pragma unroll
    for (int m = 0; m < 4; m++)
#pragma unroll
      for (int n = 0; n < 4; n++)
        acc[m][n] = __builtin_amdgcn_mfma_f32_16x16x32_bf16(af[m], bfr[n], acc[m][n], 0, 0, 0);
    cur ^= 1;
  }
#undef STAGE2

  int col0 = nb * 128 + wc * 64;
  int row0 = mb * 128 + wr * 64;
  float bbv[4];
#pragma unroll
  for (int n = 0; n < 4; n++) {
    int col = col0 + n * 16 + ln;
    bbv[n] = w0 * pb2[(size_t)e0 * HH + col] + w1r * pb2[(size_t)e1 * HH + col];
  }
#pragma unroll
  for (int m = 0; m < 4; m++) {
#pragma unroll
    for (int n = 0; n < 4; n++) {
#pragma unroll
      for (int j = 0; j < 4; j++) {
        int row = row0 + m * 16 + kq * 4 + j;
        int col = col0 + n * 16 + ln;
        out[(size_t)b * TT * HH + (size_t)row * HH + col] = acc[m][n][j] + bbv[n];
      }
    }
  }
}

extern "C" void kernel_launch(void* const* d_in, const int* in_sizes, int n_in,
                              void* d_out, int out_size, void* d_ws, size_t ws_size,
                              hipStream_t stream) {
  const float* X  = (const float*)d_in[0];
  const float* gw = (const float*)d_in[1];
  const float* w1 = (const float*)d_in[2];
  const float* pb1 = (const float*)d_in[3];
  const float* w2 = (const float*)d_in[4];
  const float* pb2 = (const float*)d_in[5];
  float* out = (float*)d_out;

  char* ws = (char*)d_ws;
  int* re = (int*)ws;                     // 16 ints: routed expert per pair
  float* rw = (float*)(ws + 64);          // 16 floats: normalized weight per pair
  float* partial = (float*)(ws + 256);    // [B][16][H] f32 = 512KB
  unsigned short* Xbf = (unsigned short*)(ws + 256 + 524288);  // [B][T][H] bf16
  const size_t fixed = 256 + 524288 + (size_t)BB * TT * HH * 2;  // 34,078,976

  unsigned short* w1t = (unsigned short*)(ws + fixed);                 // 8 experts x 8MB
  unsigned short* w2t = (unsigned short*)(ws + fixed + (size_t)EE * HH * FF * 2);
  unsigned short* hmid = (unsigned short*)(ws + fixed + (size_t)2 * EE * HH * FF * 2);
  // total: 34MB + 64MB + 64MB + 256MB = ~417MB (< ws_size, which held >570MB in R0)

  convert_x<<<8192, 256, 0, stream>>>(X, Xbf);
  mean_partial<<<dim3(16, BB), 256, 0, stream>>>(X, partial);
  gating_kernel<<<BB, 256, 0, stream>>>(partial, gw, re, rw);

  transposeE<<<dim3(HH / 32, FF / 128, EE), 256, 0, stream>>>(w1, w1t, re, HH, FF);
  transposeE<<<dim3(FF / 32, HH / 128, EE), 256, 0, stream>>>(w2, w2t, re, FF, HH);

  gemm1<<<dim3(FF / 128, TT / 128, 16), 256, 0, stream>>>(Xbf, w1t, pb1, re, rw, hmid);
  gemm2<<<dim3(HH / 128, TT / 128, BB), 256, 0, stream>>>(hmid, w2t, pb2, re, rw, out);
}

// Round 4
// 782.183 us; speedup vs baseline: 1.5697x; 1.4251x over previous
//
#include <hip/hip_runtime.h>
#include <hip/hip_bf16.h>
#include <math.h>

// Problem constants
#define BB 8
#define TT 2048
#define HH 1024
#define FF 4096
#define EE 8

typedef __attribute__((ext_vector_type(8))) short sh8;   // 8 bf16 (4 VGPRs)
typedef __attribute__((ext_vector_type(4))) float f32x4; // MFMA acc
typedef __attribute__((ext_vector_type(4))) float f4;

__device__ inline unsigned short f2bf(float f) {
  unsigned u = __builtin_bit_cast(unsigned, f);
  u += 0x7FFFu + ((u >> 16) & 1u);
  return (unsigned short)(u >> 16);
}

// async global->LDS, 16B per lane, wave-uniform LDS base + lane*16
__device__ inline void gload_lds16(const void* g, void* l) {
  __builtin_amdgcn_global_load_lds(
      (const __attribute__((address_space(1))) unsigned int*)g,
      (__attribute__((address_space(3))) unsigned int*)l, 16, 0, 0);
}

// ---------------- X f32 -> bf16 ----------------
__global__ __launch_bounds__(256) void convert_x(const float* __restrict__ X,
                                                 unsigned short* __restrict__ Xb) {
  size_t i = ((size_t)blockIdx.x * 256 + threadIdx.x) * 8;
  f4 v0 = *(const f4*)&X[i];
  f4 v1 = *(const f4*)&X[i + 4];
  sh8 o;
  o[0] = (short)f2bf(v0[0]); o[1] = (short)f2bf(v0[1]);
  o[2] = (short)f2bf(v0[2]); o[3] = (short)f2bf(v0[3]);
  o[4] = (short)f2bf(v1[0]); o[5] = (short)f2bf(v1[1]);
  o[6] = (short)f2bf(v1[2]); o[7] = (short)f2bf(v1[3]);
  *(sh8*)&Xb[i] = o;
}

// ---------------- mean over T, partial sums ----------------
__global__ __launch_bounds__(256) void mean_partial(const float* __restrict__ X,
                                                    float* __restrict__ partial) {
  int tc = blockIdx.x, b = blockIdx.y, t = threadIdx.x;
  float s0 = 0.f, s1 = 0.f, s2 = 0.f, s3 = 0.f;
  const float* base = X + (size_t)b * TT * HH + (size_t)tc * 128 * HH;
  for (int tt = 0; tt < 128; tt++) {
    const float* r = base + (size_t)tt * HH;
    s0 += r[t];
    s1 += r[t + 256];
    s2 += r[t + 512];
    s3 += r[t + 768];
  }
  float* o = partial + ((size_t)b * 16 + tc) * HH;
  o[t] = s0; o[t + 256] = s1; o[t + 512] = s2; o[t + 768] = s3;
}

// ---------------- gating: logits -> softmax -> top2 -> routing ----------------
__global__ __launch_bounds__(256) void gating_kernel(const float* __restrict__ partial,
                                                     const float* __restrict__ gw,
                                                     int* __restrict__ re,
                                                     float* __restrict__ rw) {
  int b = blockIdx.x, t = threadIdx.x;
  float acc[EE];
#pragma unroll
  for (int e = 0; e < EE; e++) acc[e] = 0.f;
  for (int jj = 0; jj < 4; jj++) {
    int h = t + jj * 256;
    float s = 0.f;
    for (int tc = 0; tc < 16; tc++) s += partial[((size_t)b * 16 + tc) * HH + h];
    s *= (1.0f / (float)TT);
#pragma unroll
    for (int e = 0; e < EE; e++) acc[e] += s * gw[h * EE + e];
  }
#pragma unroll
  for (int off = 32; off >= 1; off >>= 1) {
#pragma unroll
    for (int e = 0; e < EE; e++) acc[e] += __shfl_down(acc[e], off);
  }
  __shared__ float red[4][EE];
  if ((t & 63) == 0) {
#pragma unroll
    for (int e = 0; e < EE; e++) red[t >> 6][e] = acc[e];
  }
  __syncthreads();
  if (t == 0) {
    float lg[EE];
#pragma unroll
    for (int e = 0; e < EE; e++) lg[e] = red[0][e] + red[1][e] + red[2][e] + red[3][e];
    float mx = lg[0];
#pragma unroll
    for (int e = 1; e < EE; e++) mx = fmaxf(mx, lg[e]);
    float p[EE]; float s = 0.f;
#pragma unroll
    for (int e = 0; e < EE; e++) { p[e] = expf(lg[e] - mx); s += p[e]; }
#pragma unroll
    for (int e = 0; e < EE; e++) p[e] /= s;
    int i1 = 0;
#pragma unroll
    for (int e = 1; e < EE; e++) if (p[e] > p[i1]) i1 = e;  // first index wins ties
    int i2 = -1;
#pragma unroll
    for (int e = 0; e < EE; e++) {
      if (e == i1) continue;
      if (i2 < 0 || p[e] > p[i2]) i2 = e;
    }
    float den = p[i1] + p[i2];
    re[b * 2 + 0] = i1; rw[b * 2 + 0] = p[i1] / den;
    re[b * 2 + 1] = i2; rw[b * 2 + 1] = p[i2] / den;
  }
}

// ---------------- transpose+convert per-EXPERT weights: W[e][K][N] f32 -> Wt[e][N][K] bf16
__global__ __launch_bounds__(256) void transposeE(const float* __restrict__ W,
                                                  unsigned short* __restrict__ Wt,
                                                  const int* __restrict__ re,
                                                  int K, int N) {
  int e = blockIdx.z;
  bool u = false;
#pragma unroll
  for (int p = 0; p < 16; p++) u = u || (re[p] == e);
  if (!u) return;

  __shared__ float tile[64][65];
  int kb = blockIdx.x, nb = blockIdx.y;
  const float* src = W + (size_t)e * K * N + (size_t)(kb * 64) * N + nb * 64;
  int t = threadIdx.x;
#pragma unroll
  for (int pass = 0; pass < 4; pass++) {
    int r = (t >> 4) + pass * 16;
    int c = (t & 15) * 4;
    *(f4*)&tile[r][c] = *(const f4*)&src[(size_t)r * N + c];
  }
  __syncthreads();
#pragma unroll
  for (int pass = 0; pass < 2; pass++) {
    int idx = (t + pass * 256) * 8;
    int nl = idx >> 6, k0 = idx & 63;
    sh8 o;
#pragma unroll
    for (int j = 0; j < 8; j++) o[j] = (short)f2bf(tile[k0 + j][nl]);
    *(sh8*)&Wt[(size_t)e * N * K + (size_t)(nb * 64 + nl) * K + kb * 64 + k0] = o;
  }
}

// ================= 256x256 8-phase counted-vmcnt GEMM (T1+T2+T3+T4+T5) =================
// MODE 0: hmid[pair] = rw * gelu(X[b] @ w1t[e]^T + b1[e])   (bf16 out)
// MODE 1: out[b] = hmid[2b]|hmid[2b+1] (K-concat) @ w2t^T + weighted b2   (f32 out)
// LDS 128KB: A[2][256][64] + B[2][256][64] bf16, XOR swizzle byte ^= (row&7)<<4
// applied as inverse-swizzled GLOBAL SOURCE (gload_lds dest stays linear) + swizzled ds_read.
// vmcnt ledger (per thread, 2 loads per stage unit):
//   prologue: 12 issued, vmcnt(4) -> tile0 complete, tile1 q0 (4) in flight.
//   steady iter: phases 1-4 issue 4 units; phase4 vmcnt(4) -> tile T+1 complete,
//   tile T+2 q0 in flight; phases 5-8 same one tile later.
//   TAIL (T=NT-2): only tile NT-1 q1 staged (phases 1-2) -> 8 outstanding at
//   phase 4; vmcnt(0) there drains ALL of tile NT-1 (the round-3 bug was
//   vmcnt(4) here, leaving q1 units un-drained -> stale LDS reads).

#define PHASE(qm, qn, buf, STMT, VM) do {                                          \
    sh8 afr[4][2], bfr[2][2];                                                      \
    _Pragma("unroll")                                                              \
    for (int m4 = 0; m4 < 4; m4++) {                                               \
      int row = wr * 128 + (qm) * 64 + m4 * 16 + ln;                               \
      _Pragma("unroll")                                                            \
      for (int kk = 0; kk < 2; kk++) {                                             \
        int cp = (kk * 4 + kq) ^ (row & 7);                                        \
        afr[m4][kk] = *(const sh8*)(ldsA + (buf) * 32768 + row * 128 + cp * 16);   \
      }                                                                            \
    }                                                                              \
    _Pragma("unroll")                                                              \
    for (int n2 = 0; n2 < 2; n2++) {                                               \
      int row = wc * 64 + (qn) * 32 + n2 * 16 + ln;                                \
      _Pragma("unroll")                                                            \
      for (int kk = 0; kk < 2; kk++) {                                             \
        int cp = (kk * 4 + kq) ^ (row & 7);                                        \
        bfr[n2][kk] = *(const sh8*)(ldsB + (buf) * 32768 + row * 128 + cp * 16);   \
      }                                                                            \
    }                                                                              \
    STMT;                                                                          \
    __builtin_amdgcn_sched_barrier(0);                                             \
    __builtin_amdgcn_s_barrier();                                                  \
    asm volatile("s_waitcnt lgkmcnt(0)" ::: "memory");                             \
    __builtin_amdgcn_sched_barrier(0);                                             \
    __builtin_amdgcn_s_setprio(1);                                                 \
    _Pragma("unroll")                                                              \
    for (int m4 = 0; m4 < 4; m4++)                                                 \
      _Pragma("unroll")                                                            \
      for (int n2 = 0; n2 < 2; n2++)                                               \
        _Pragma("unroll")                                                          \
        for (int kk = 0; kk < 2; kk++)                                             \
          acc[(qm) * 4 + m4][(qn) * 2 + n2] =                                      \
              __builtin_amdgcn_mfma_f32_16x16x32_bf16(                             \
                  afr[m4][kk], bfr[n2][kk], acc[(qm) * 4 + m4][(qn) * 2 + n2],     \
                  0, 0, 0);                                                        \
    __builtin_amdgcn_s_setprio(0);                                                 \
    if ((VM) == 4) { asm volatile("s_waitcnt vmcnt(4)" ::: "memory"); }            \
    else if ((VM) == 1) { asm volatile("s_waitcnt vmcnt(0)" ::: "memory"); }       \
    __builtin_amdgcn_sched_barrier(0);                                             \
    __builtin_amdgcn_s_barrier();                                                  \
  } while (0)

template <int MODE>
__global__ __launch_bounds__(512, 1) void gemm8p(
    const unsigned short* __restrict__ XorH,   // MODE0: Xbf ; MODE1: hmid
    const unsigned short* __restrict__ Wt,     // MODE0: w1t ; MODE1: w2t
    const float* __restrict__ bias,            // MODE0: pb1 ; MODE1: pb2
    const int* __restrict__ re,
    const float* __restrict__ rw,
    unsigned short* __restrict__ hmid_out,     // MODE0 out
    float* __restrict__ out) {                 // MODE1 out
  extern __shared__ char lds[];
  char* ldsA = lds;            // [2][256][64] bf16 = 2x32KB
  char* ldsB = lds + 65536;    // [2][256][64] bf16 = 2x32KB

  constexpr int NT  = (MODE == 0) ? (HH / 64) : (2 * FF / 64);  // 16 / 128
  constexpr int NTH = (MODE == 0) ? NT : (FF / 64);             // 16 / 64

  int P = blockIdx.x;
  int t = threadIdx.x;
  int lane = t & 63, wv = t >> 6;
  int wr = wv >> 2, wc = wv & 3;       // 2M x 4N waves
  int ln = lane & 15, kq = lane >> 4;

  const unsigned short *A0p, *A1p, *B0p, *B1p;
  int lda, ldb;
  int pair = 0, b, e0, e1, mb, nb;
  if constexpr (MODE == 0) {
    pair = (P & 7) * 2 + ((P >> 3) & 1);    // XCD <-> batch (pairs 2b,2b+1 share XCD)
    int idx = P >> 4;
    nb = idx & 15; mb = idx >> 4;
    b = pair >> 1;
    e0 = re[pair]; e1 = e0;
    A0p = XorH + (size_t)b * TT * HH + (size_t)mb * 256 * HH; A1p = A0p; lda = HH;
    B0p = Wt + (size_t)e0 * FF * HH + (size_t)nb * 256 * HH; B1p = B0p; ldb = HH;
  } else {
    b = P & 7;                               // XCD <-> batch
    int idx = P >> 3;
    nb = idx & 3; mb = idx >> 2;
    e0 = re[2 * b]; e1 = re[2 * b + 1];
    A0p = XorH + (size_t)(2 * b) * TT * FF + (size_t)mb * 256 * FF;
    A1p = A0p + (size_t)TT * FF; lda = FF;
    B0p = Wt + (size_t)e0 * FF * HH + (size_t)nb * 256 * FF;
    B1p = Wt + (size_t)e1 * FF * HH + (size_t)nb * 256 * FF; ldb = FF;
  }

  // stage unit = 2 gload_lds16 per thread (16KB). A unit q: rows {q*64..+63, 128+q*64..+63}.
  auto stageA = [&](int tau, int q) {
    int buf = tau & 1;
    const unsigned short* Ap = (tau < NTH) ? A0p : A1p;
    int kt = (tau < NTH) ? tau : tau - NTH;
#pragma unroll
    for (int ld = 0; ld < 2; ld++) {
      int row = ld * 128 + q * 64 + (t >> 3);
      int cl = (t & 7) ^ (row & 7);
      gload_lds16(Ap + (size_t)row * lda + kt * 64 + cl * 8,
                  ldsA + buf * 32768 + row * 128 + (t & 7) * 16);
    }
  };
  // B unit q: rows {j*64 + q*32 .. +31 : j=0..3}
  auto stageB = [&](int tau, int q) {
    int buf = tau & 1;
    const unsigned short* Bp = (tau < NTH) ? B0p : B1p;
    int kt = (tau < NTH) ? tau : tau - NTH;
#pragma unroll
    for (int ld = 0; ld < 2; ld++) {
      int j = ld * 2 + (t >> 8);
      int row = j * 64 + q * 32 + ((t >> 3) & 31);
      int cl = (t & 7) ^ (row & 7);
      gload_lds16(Bp + (size_t)row * ldb + kt * 64 + cl * 8,
                  ldsB + buf * 32768 + row * 128 + (t & 7) * 16);
    }
  };

  f32x4 acc[8][4];
#pragma unroll
  for (int m = 0; m < 8; m++)
#pragma unroll
    for (int n = 0; n < 4; n++) acc[m][n] = (f32x4){0.f, 0.f, 0.f, 0.f};

  // Prologue: tile0 fully (4 units), tile1 A0',B0' (2 units). vmcnt(4)=2 units pending.
  stageA(0, 0); stageB(0, 0); stageA(0, 1); stageB(0, 1);
  stageA(1, 0); stageB(1, 0);
  asm volatile("s_waitcnt vmcnt(4)" ::: "memory");
  __builtin_amdgcn_sched_barrier(0);
  __builtin_amdgcn_s_barrier();

  int T = 0;
  for (; T + 2 < NT; T += 2) {            // steady: T = 0 .. NT-4
    PHASE(0, 0, 0, { stageA(T + 1, 1); }, 0);
    PHASE(0, 1, 0, { stageB(T + 1, 1); }, 0);
    PHASE(1, 0, 0, { stageA(T + 2, 0); }, 0);
    PHASE(1, 1, 0, { stageB(T + 2, 0); }, 4);   // vmcnt(4): tile T+1 complete
    PHASE(0, 0, 1, { stageA(T + 2, 1); }, 0);
    PHASE(0, 1, 1, { stageB(T + 2, 1); }, 0);
    PHASE(1, 0, 1, { stageA(T + 3, 0); }, 0);
    PHASE(1, 1, 1, { stageB(T + 3, 0); }, 4);   // vmcnt(4): tile T+2 complete
  }
  // Peeled tail: T == NT-2. Only tile NT-1 q1 remains to stage.
  PHASE(0, 0, 0, { stageA(T + 1, 1); }, 0);
  PHASE(0, 1, 0, { stageB(T + 1, 1); }, 0);
  PHASE(1, 0, 0, {}, 0);
  PHASE(1, 1, 0, {}, 1);                        // vmcnt(0): tile NT-1 FULLY staged
  PHASE(0, 0, 1, {}, 0);
  PHASE(0, 1, 1, {}, 0);
  PHASE(1, 0, 1, {}, 0);
  PHASE(1, 1, 1, {}, 0);

  // Epilogue
  if constexpr (MODE == 0) {
    float wgt = rw[pair];
    unsigned short* Cout = hmid_out + (size_t)pair * TT * FF;
#pragma unroll
    for (int nn = 0; nn < 4; nn++) {
      int col = nb * 256 + wc * 64 + nn * 16 + ln;
      float bv = bias[(size_t)e0 * FF + col];
#pragma unroll
      for (int mm = 0; mm < 8; mm++) {
#pragma unroll
        for (int j = 0; j < 4; j++) {
          int row = mb * 256 + wr * 128 + mm * 16 + kq * 4 + j;
          float v = acc[mm][nn][j] + bv;
          float g = 0.5f * v * (1.0f + erff(v * 0.70710678118654752f));
          Cout[(size_t)row * FF + col] = f2bf(wgt * g);
        }
      }
    }
  } else {
    float w0 = rw[2 * b], w1v = rw[2 * b + 1];
#pragma unroll
    for (int nn = 0; nn < 4; nn++) {
      int col = nb * 256 + wc * 64 + nn * 16 + ln;
      float bv = w0 * bias[(size_t)e0 * HH + col] + w1v * bias[(size_t)e1 * HH + col];
#pragma unroll
      for (int mm = 0; mm < 8; mm++) {
#pragma unroll
        for (int j = 0; j < 4; j++) {
          int row = mb * 256 + wr * 128 + mm * 16 + kq * 4 + j;
          out[(size_t)b * TT * HH + (size_t)row * HH + col] = acc[mm][nn][j] + bv;
        }
      }
    }
  }
}

extern "C" void kernel_launch(void* const* d_in, const int* in_sizes, int n_in,
                              void* d_out, int out_size, void* d_ws, size_t ws_size,
                              hipStream_t stream) {
  const float* X  = (const float*)d_in[0];
  const float* gw = (const float*)d_in[1];
  const float* w1 = (const float*)d_in[2];
  const float* pb1 = (const float*)d_in[3];
  const float* w2 = (const float*)d_in[4];
  const float* pb2 = (const float*)d_in[5];
  float* out = (float*)d_out;

  char* ws = (char*)d_ws;
  int* re = (int*)ws;                     // 16 ints
  float* rw = (float*)(ws + 64);          // 16 floats
  float* partial = (float*)(ws + 256);    // [B][16][H] f32 = 512KB
  unsigned short* Xbf = (unsigned short*)(ws + 256 + 524288);  // [B][T][H] bf16 = 32MB
  const size_t fixed = 256 + 524288 + (size_t)BB * TT * HH * 2;

  unsigned short* w1t = (unsigned short*)(ws + fixed);                          // 64MB
  unsigned short* w2t = (unsigned short*)(ws + fixed + (size_t)EE * HH * FF * 2);
  unsigned short* hmid = (unsigned short*)(ws + fixed + (size_t)2 * EE * HH * FF * 2); // 256MB

  hipFuncSetAttribute((const void*)gemm8p<0>,
                      hipFuncAttributeMaxDynamicSharedMemorySize, 131072);
  hipFuncSetAttribute((const void*)gemm8p<1>,
                      hipFuncAttributeMaxDynamicSharedMemorySize, 131072);

  convert_x<<<8192, 256, 0, stream>>>(X, Xbf);
  mean_partial<<<dim3(16, BB), 256, 0, stream>>>(X, partial);
  gating_kernel<<<BB, 256, 0, stream>>>(partial, gw, re, rw);

  transposeE<<<dim3(HH / 64, FF / 64, EE), 256, 0, stream>>>(w1, w1t, re, HH, FF);
  transposeE<<<dim3(FF / 64, HH / 64, EE), 256, 0, stream>>>(w2, w2t, re, FF, HH);

  gemm8p<0><<<2048, 512, 131072, stream>>>(Xbf, w1t, pb1, re, rw, hmid, nullptr);
  gemm8p<1><<<256, 512, 131072, stream>>>(hmid, w2t, pb2, re, rw, nullptr, out);
}

// Round 5
// 729.842 us; speedup vs baseline: 1.6823x; 1.0717x over previous
//
#include <hip/hip_runtime.h>
#include <hip/hip_bf16.h>
#include <math.h>

// Problem constants
#define BB 8
#define TT 2048
#define HH 1024
#define FF 4096
#define EE 8

typedef __attribute__((ext_vector_type(8))) short sh8;   // 8 bf16 (4 VGPRs)
typedef __attribute__((ext_vector_type(4))) float f32x4; // MFMA acc
typedef __attribute__((ext_vector_type(4))) float f4;

__device__ inline unsigned short f2bf(float f) {
  unsigned u = __builtin_bit_cast(unsigned, f);
  u += 0x7FFFu + ((u >> 16) & 1u);
  return (unsigned short)(u >> 16);
}

// A&S 7.1.26 erf approximation, |err| <= 1.5e-7, branchless.
__device__ inline float erf_fast(float x) {
  float ax = fabsf(x);
  float t = 1.0f / (1.0f + 0.3275911f * ax);
  float y = t * (0.254829592f +
           t * (-0.284496736f +
           t * (1.421413741f +
           t * (-1.453152027f +
           t * 1.061405429f))));
  float e = __expf(-ax * ax);
  float r = 1.0f - y * e;
  return copysignf(r, x);
}

// async global->LDS, 16B per lane, wave-uniform LDS base + lane*16
__device__ inline void gload_lds16(const void* g, void* l) {
  __builtin_amdgcn_global_load_lds(
      (const __attribute__((address_space(1))) unsigned int*)g,
      (__attribute__((address_space(3))) unsigned int*)l, 16, 0, 0);
}

// ---------------- X f32 -> bf16 ----------------
__global__ __launch_bounds__(256) void convert_x(const float* __restrict__ X,
                                                 unsigned short* __restrict__ Xb) {
  size_t i = ((size_t)blockIdx.x * 256 + threadIdx.x) * 8;
  f4 v0 = *(const f4*)&X[i];
  f4 v1 = *(const f4*)&X[i + 4];
  sh8 o;
  o[0] = (short)f2bf(v0[0]); o[1] = (short)f2bf(v0[1]);
  o[2] = (short)f2bf(v0[2]); o[3] = (short)f2bf(v0[3]);
  o[4] = (short)f2bf(v1[0]); o[5] = (short)f2bf(v1[1]);
  o[6] = (short)f2bf(v1[2]); o[7] = (short)f2bf(v1[3]);
  *(sh8*)&Xb[i] = o;
}

// ---------------- mean over T, partial sums ----------------
__global__ __launch_bounds__(256) void mean_partial(const float* __restrict__ X,
                                                    float* __restrict__ partial) {
  int tc = blockIdx.x, b = blockIdx.y, t = threadIdx.x;
  float s0 = 0.f, s1 = 0.f, s2 = 0.f, s3 = 0.f;
  const float* base = X + (size_t)b * TT * HH + (size_t)tc * 128 * HH;
  for (int tt = 0; tt < 128; tt++) {
    const float* r = base + (size_t)tt * HH;
    s0 += r[t];
    s1 += r[t + 256];
    s2 += r[t + 512];
    s3 += r[t + 768];
  }
  float* o = partial + ((size_t)b * 16 + tc) * HH;
  o[t] = s0; o[t + 256] = s1; o[t + 512] = s2; o[t + 768] = s3;
}

// ---------------- gating: logits -> softmax -> top2 -> routing ----------------
__global__ __launch_bounds__(256) void gating_kernel(const float* __restrict__ partial,
                                                     const float* __restrict__ gw,
                                                     int* __restrict__ re,
                                                     float* __restrict__ rw) {
  int b = blockIdx.x, t = threadIdx.x;
  float acc[EE];
#pragma unroll
  for (int e = 0; e < EE; e++) acc[e] = 0.f;
  for (int jj = 0; jj < 4; jj++) {
    int h = t + jj * 256;
    float s = 0.f;
    for (int tc = 0; tc < 16; tc++) s += partial[((size_t)b * 16 + tc) * HH + h];
    s *= (1.0f / (float)TT);
#pragma unroll
    for (int e = 0; e < EE; e++) acc[e] += s * gw[h * EE + e];
  }
#pragma unroll
  for (int off = 32; off >= 1; off >>= 1) {
#pragma unroll
    for (int e = 0; e < EE; e++) acc[e] += __shfl_down(acc[e], off);
  }
  __shared__ float red[4][EE];
  if ((t & 63) == 0) {
#pragma unroll
    for (int e = 0; e < EE; e++) red[t >> 6][e] = acc[e];
  }
  __syncthreads();
  if (t == 0) {
    float lg[EE];
#pragma unroll
    for (int e = 0; e < EE; e++) lg[e] = red[0][e] + red[1][e] + red[2][e] + red[3][e];
    float mx = lg[0];
#pragma unroll
    for (int e = 1; e < EE; e++) mx = fmaxf(mx, lg[e]);
    float p[EE]; float s = 0.f;
#pragma unroll
    for (int e = 0; e < EE; e++) { p[e] = expf(lg[e] - mx); s += p[e]; }
#pragma unroll
    for (int e = 0; e < EE; e++) p[e] /= s;
    int i1 = 0;
#pragma unroll
    for (int e = 1; e < EE; e++) if (p[e] > p[i1]) i1 = e;  // first index wins ties
    int i2 = -1;
#pragma unroll
    for (int e = 0; e < EE; e++) {
      if (e == i1) continue;
      if (i2 < 0 || p[e] > p[i2]) i2 = e;
    }
    float den = p[i1] + p[i2];
    re[b * 2 + 0] = i1; rw[b * 2 + 0] = p[i1] / den;
    re[b * 2 + 1] = i2; rw[b * 2 + 1] = p[i2] / den;
  }
}

// ---------------- transpose+convert per-EXPERT weights: W[e][K][N] f32 -> Wt[e][N][K] bf16
__global__ __launch_bounds__(256) void transposeE(const float* __restrict__ W,
                                                  unsigned short* __restrict__ Wt,
                                                  const int* __restrict__ re,
                                                  int K, int N) {
  int e = blockIdx.z;
  bool u = false;
#pragma unroll
  for (int p = 0; p < 16; p++) u = u || (re[p] == e);
  if (!u) return;

  __shared__ float tile[64][65];
  int kb = blockIdx.x, nb = blockIdx.y;
  const float* src = W + (size_t)e * K * N + (size_t)(kb * 64) * N + nb * 64;
  int t = threadIdx.x;
#pragma unroll
  for (int pass = 0; pass < 4; pass++) {
    int r = (t >> 4) + pass * 16;
    int c = (t & 15) * 4;
    *(f4*)&tile[r][c] = *(const f4*)&src[(size_t)r * N + c];
  }
  __syncthreads();
#pragma unroll
  for (int pass = 0; pass < 2; pass++) {
    int idx = (t + pass * 256) * 8;
    int nl = idx >> 6, k0 = idx & 63;
    sh8 o;
#pragma unroll
    for (int j = 0; j < 8; j++) o[j] = (short)f2bf(tile[k0 + j][nl]);
    *(sh8*)&Wt[(size_t)e * N * K + (size_t)(nb * 64 + nl) * K + kb * 64 + k0] = o;
  }
}

// ================= 256x256 8-phase counted-vmcnt GEMM (T1+T2+T3+T4+T5) =================
// MODE 0: hmid[pair] = rw * gelu(X[b] @ w1t[e]^T + b1[e])   (bf16 out, LDS-staged epilogue)
// MODE 1: out[b] = hmid[2b]|hmid[2b+1] (K-concat) @ w2t^T + weighted b2   (f32 out)
// LDS 128KB: A[2][256][64] + B[2][256][64] bf16, XOR swizzle byte ^= (row&7)<<4
// applied as inverse-swizzled GLOBAL SOURCE (gload_lds dest stays linear) + swizzled ds_read.
// vmcnt ledger: prologue 12 issued, vmcnt(4); steady: 4 units/tile-half, vmcnt(4) at
// phases 4/8; peeled tail stages only tile NT-1 q1 and uses vmcnt(0) at phase 4.

#define PHASE(qm, qn, buf, STMT, VM) do {                                          \
    sh8 afr[4][2], bfr[2][2];                                                      \
    _Pragma("unroll")                                                              \
    for (int m4 = 0; m4 < 4; m4++) {                                               \
      int row = wr * 128 + (qm) * 64 + m4 * 16 + ln;                               \
      _Pragma("unroll")                                                            \
      for (int kk = 0; kk < 2; kk++) {                                             \
        int cp = (kk * 4 + kq) ^ (row & 7);                                        \
        afr[m4][kk] = *(const sh8*)(ldsA + (buf) * 32768 + row * 128 + cp * 16);   \
      }                                                                            \
    }                                                                              \
    _Pragma("unroll")                                                              \
    for (int n2 = 0; n2 < 2; n2++) {                                               \
      int row = wc * 64 + (qn) * 32 + n2 * 16 + ln;                                \
      _Pragma("unroll")                                                            \
      for (int kk = 0; kk < 2; kk++) {                                             \
        int cp = (kk * 4 + kq) ^ (row & 7);                                        \
        bfr[n2][kk] = *(const sh8*)(ldsB + (buf) * 32768 + row * 128 + cp * 16);   \
      }                                                                            \
    }                                                                              \
    STMT;                                                                          \
    __builtin_amdgcn_sched_barrier(0);                                             \
    __builtin_amdgcn_s_barrier();                                                  \
    asm volatile("s_waitcnt lgkmcnt(0)" ::: "memory");                             \
    __builtin_amdgcn_sched_barrier(0);                                             \
    __builtin_amdgcn_s_setprio(1);                                                 \
    _Pragma("unroll")                                                              \
    for (int m4 = 0; m4 < 4; m4++)                                                 \
      _Pragma("unroll")                                                            \
      for (int n2 = 0; n2 < 2; n2++)                                               \
        _Pragma("unroll")                                                          \
        for (int kk = 0; kk < 2; kk++)                                             \
          acc[(qm) * 4 + m4][(qn) * 2 + n2] =                                      \
              __builtin_amdgcn_mfma_f32_16x16x32_bf16(                             \
                  afr[m4][kk], bfr[n2][kk], acc[(qm) * 4 + m4][(qn) * 2 + n2],     \
                  0, 0, 0);                                                        \
    __builtin_amdgcn_s_setprio(0);                                                 \
    if ((VM) == 4) { asm volatile("s_waitcnt vmcnt(4)" ::: "memory"); }            \
    else if ((VM) == 1) { asm volatile("s_waitcnt vmcnt(0)" ::: "memory"); }       \
    __builtin_amdgcn_sched_barrier(0);                                             \
    __builtin_amdgcn_s_barrier();                                                  \
  } while (0)

template <int MODE>
__global__ __launch_bounds__(512, 1) void gemm8p(
    const unsigned short* __restrict__ XorH,   // MODE0: Xbf ; MODE1: hmid
    const unsigned short* __restrict__ Wt,     // MODE0: w1t ; MODE1: w2t
    const float* __restrict__ bias,            // MODE0: pb1 ; MODE1: pb2
    const int* __restrict__ re,
    const float* __restrict__ rw,
    unsigned short* __restrict__ hmid_out,     // MODE0 out
    float* __restrict__ out) {                 // MODE1 out
  extern __shared__ char lds[];
  char* ldsA = lds;            // [2][256][64] bf16 = 2x32KB
  char* ldsB = lds + 65536;    // [2][256][64] bf16 = 2x32KB

  constexpr int NT  = (MODE == 0) ? (HH / 64) : (2 * FF / 64);  // 16 / 128
  constexpr int NTH = (MODE == 0) ? NT : (FF / 64);             // 16 / 64

  int P = blockIdx.x;
  int t = threadIdx.x;
  int lane = t & 63, wv = t >> 6;
  int wr = wv >> 2, wc = wv & 3;       // 2M x 4N waves
  int ln = lane & 15, kq = lane >> 4;

  const unsigned short *A0p, *A1p, *B0p, *B1p;
  int lda, ldb;
  int pair = 0, b, e0, e1, mb, nb;
  if constexpr (MODE == 0) {
    pair = (P & 7) * 2 + ((P >> 3) & 1);    // XCD <-> batch (pairs 2b,2b+1 share XCD)
    int idx = P >> 4;
    mb = idx & 7; nb = idx >> 3;            // mb FAST: concurrent gen shares B panels
    b = pair >> 1;
    e0 = re[pair]; e1 = e0;
    A0p = XorH + (size_t)b * TT * HH + (size_t)mb * 256 * HH; A1p = A0p; lda = HH;
    B0p = Wt + (size_t)e0 * FF * HH + (size_t)nb * 256 * HH; B1p = B0p; ldb = HH;
  } else {
    b = P & 7;                               // XCD <-> batch
    int idx = P >> 3;
    nb = idx & 3; mb = idx >> 2;
    e0 = re[2 * b]; e1 = re[2 * b + 1];
    A0p = XorH + (size_t)(2 * b) * TT * FF + (size_t)mb * 256 * FF;
    A1p = A0p + (size_t)TT * FF; lda = FF;
    B0p = Wt + (size_t)e0 * FF * HH + (size_t)nb * 256 * FF;
    B1p = Wt + (size_t)e1 * FF * HH + (size_t)nb * 256 * FF; ldb = FF;
  }

  // stage unit = 2 gload_lds16 per thread (16KB). A unit q: rows {q*64..+63, 128+q*64..+63}.
  auto stageA = [&](int tau, int q) {
    int buf = tau & 1;
    const unsigned short* Ap = (tau < NTH) ? A0p : A1p;
    int kt = (tau < NTH) ? tau : tau - NTH;
#pragma unroll
    for (int ld = 0; ld < 2; ld++) {
      int row = ld * 128 + q * 64 + (t >> 3);
      int cl = (t & 7) ^ (row & 7);
      gload_lds16(Ap + (size_t)row * lda + kt * 64 + cl * 8,
                  ldsA + buf * 32768 + row * 128 + (t & 7) * 16);
    }
  };
  // B unit q: rows {j*64 + q*32 .. +31 : j=0..3}
  auto stageB = [&](int tau, int q) {
    int buf = tau & 1;
    const unsigned short* Bp = (tau < NTH) ? B0p : B1p;
    int kt = (tau < NTH) ? tau : tau - NTH;
#pragma unroll
    for (int ld = 0; ld < 2; ld++) {
      int j = ld * 2 + (t >> 8);
      int row = j * 64 + q * 32 + ((t >> 3) & 31);
      int cl = (t & 7) ^ (row & 7);
      gload_lds16(Bp + (size_t)row * ldb + kt * 64 + cl * 8,
                  ldsB + buf * 32768 + row * 128 + (t & 7) * 16);
    }
  };

  f32x4 acc[8][4];
#pragma unroll
  for (int m = 0; m < 8; m++)
#pragma unroll
    for (int n = 0; n < 4; n++) acc[m][n] = (f32x4){0.f, 0.f, 0.f, 0.f};

  // Prologue: tile0 fully (4 units), tile1 A0',B0' (2 units). vmcnt(4)=2 units pending.
  stageA(0, 0); stageB(0, 0); stageA(0, 1); stageB(0, 1);
  stageA(1, 0); stageB(1, 0);
  asm volatile("s_waitcnt vmcnt(4)" ::: "memory");
  __builtin_amdgcn_sched_barrier(0);
  __builtin_amdgcn_s_barrier();

  int T = 0;
  for (; T + 2 < NT; T += 2) {            // steady: T = 0 .. NT-4
    PHASE(0, 0, 0, { stageA(T + 1, 1); }, 0);
    PHASE(0, 1, 0, { stageB(T + 1, 1); }, 0);
    PHASE(1, 0, 0, { stageA(T + 2, 0); }, 0);
    PHASE(1, 1, 0, { stageB(T + 2, 0); }, 4);   // vmcnt(4): tile T+1 complete
    PHASE(0, 0, 1, { stageA(T + 2, 1); }, 0);
    PHASE(0, 1, 1, { stageB(T + 2, 1); }, 0);
    PHASE(1, 0, 1, { stageA(T + 3, 0); }, 0);
    PHASE(1, 1, 1, { stageB(T + 3, 0); }, 4);   // vmcnt(4): tile T+2 complete
  }
  // Peeled tail: T == NT-2. Only tile NT-1 q1 remains to stage.
  PHASE(0, 0, 0, { stageA(T + 1, 1); }, 0);
  PHASE(0, 1, 0, { stageB(T + 1, 1); }, 0);
  PHASE(1, 0, 0, {}, 0);
  PHASE(1, 1, 0, {}, 1);                        // vmcnt(0): tile NT-1 FULLY staged
  PHASE(0, 0, 1, {}, 0);
  PHASE(0, 1, 1, {}, 0);
  PHASE(1, 0, 1, {}, 0);
  PHASE(1, 1, 1, {}, 0);

  // Epilogue
  if constexpr (MODE == 0) {
    float wgt = rw[pair];
    unsigned short* Cout = hmid_out + (size_t)pair * TT * FF;
    float bbv[4];
#pragma unroll
    for (int nn = 0; nn < 4; nn++)
      bbv[nn] = bias[(size_t)e0 * FF + nb * 256 + wc * 64 + nn * 16 + ln];
    // LDS-staged packed store: K-loop LDS (128KB) is dead; 256x256 bf16 tile = 128KB.
    // value(r,c) at lds byte r*512 + ((c*2) ^ (((r>>2)&7)<<4)); bijective per row.
    __syncthreads();
#pragma unroll
    for (int mm = 0; mm < 8; mm++) {
#pragma unroll
      for (int nn = 0; nn < 4; nn++) {
        int c2 = (wc * 64 + nn * 16 + ln) * 2;
#pragma unroll
        for (int j = 0; j < 4; j++) {
          int r = wr * 128 + mm * 16 + kq * 4 + j;
          float v = acc[mm][nn][j] + bbv[nn];
          float g = 0.5f * v * (1.0f + erf_fast(v * 0.70710678118654752f));
          *(unsigned short*)(lds + r * 512 + (c2 ^ (((r >> 2) & 7) << 4))) =
              f2bf(wgt * g);
        }
      }
    }
    __syncthreads();
#pragma unroll
    for (int i = 0; i < 16; i++) {
      int r = wv * 32 + i * 2 + (lane >> 5);
      int ci = lane & 31;
      sh8 v = *(const sh8*)(lds + r * 512 + ((ci ^ ((r >> 2) & 7)) << 4));
      *(sh8*)&Cout[(size_t)(mb * 256 + r) * FF + nb * 256 + ci * 8] = v;
    }
  } else {
    float w0 = rw[2 * b], w1v = rw[2 * b + 1];
#pragma unroll
    for (int nn = 0; nn < 4; nn++) {
      int col = nb * 256 + wc * 64 + nn * 16 + ln;
      float bv = w0 * bias[(size_t)e0 * HH + col] + w1v * bias[(size_t)e1 * HH + col];
#pragma unroll
      for (int mm = 0; mm < 8; mm++) {
#pragma unroll
        for (int j = 0; j < 4; j++) {
          int row = mb * 256 + wr * 128 + mm * 16 + kq * 4 + j;
          out[(size_t)b * TT * HH + (size_t)row * HH + col] = acc[mm][nn][j] + bv;
        }
      }
    }
  }
}

extern "C" void kernel_launch(void* const* d_in, const int* in_sizes, int n_in,
                              void* d_out, int out_size, void* d_ws, size_t ws_size,
                              hipStream_t stream) {
  const float* X  = (const float*)d_in[0];
  const float* gw = (const float*)d_in[1];
  const float* w1 = (const float*)d_in[2];
  const float* pb1 = (const float*)d_in[3];
  const float* w2 = (const float*)d_in[4];
  const float* pb2 = (const float*)d_in[5];
  float* out = (float*)d_out;

  char* ws = (char*)d_ws;
  int* re = (int*)ws;                     // 16 ints
  float* rw = (float*)(ws + 64);          // 16 floats
  float* partial = (float*)(ws + 256);    // [B][16][H] f32 = 512KB
  unsigned short* Xbf = (unsigned short*)(ws + 256 + 524288);  // [B][T][H] bf16 = 32MB
  const size_t fixed = 256 + 524288 + (size_t)BB * TT * HH * 2;

  unsigned short* w1t = (unsigned short*)(ws + fixed);                          // 64MB
  unsigned short* w2t = (unsigned short*)(ws + fixed + (size_t)EE * HH * FF * 2);
  unsigned short* hmid = (unsigned short*)(ws + fixed + (size_t)2 * EE * HH * FF * 2); // 256MB

  hipFuncSetAttribute((const void*)gemm8p<0>,
                      hipFuncAttributeMaxDynamicSharedMemorySize, 131072);
  hipFuncSetAttribute((const void*)gemm8p<1>,
                      hipFuncAttributeMaxDynamicSharedMemorySize, 131072);

  convert_x<<<8192, 256, 0, stream>>>(X, Xbf);
  mean_partial<<<dim3(16, BB), 256, 0, stream>>>(X, partial);
  gating_kernel<<<BB, 256, 0, stream>>>(partial, gw, re, rw);

  transposeE<<<dim3(HH / 64, FF / 64, EE), 256, 0, stream>>>(w1, w1t, re, HH, FF);
  transposeE<<<dim3(FF / 64, HH / 64, EE), 256, 0, stream>>>(w2, w2t, re, FF, HH);

  gemm8p<0><<<2048, 512, 131072, stream>>>(Xbf, w1t, pb1, re, rw, hmid, nullptr);
  gemm8p<1><<<256, 512, 131072, stream>>>(hmid, w2t, pb2, re, rw, nullptr, out);
}

// Round 6
// 724.285 us; speedup vs baseline: 1.6952x; 1.0077x over previous
//
#include <hip/hip_runtime.h>
#include <hip/hip_bf16.h>
#include <math.h>

// Problem constants
#define BB 8
#define TT 2048
#define HH 1024
#define FF 4096
#define EE 8

typedef __attribute__((ext_vector_type(8))) short sh8;   // 8 bf16 (4 VGPRs)
typedef __attribute__((ext_vector_type(4))) float f32x4; // MFMA acc
typedef __attribute__((ext_vector_type(4))) float f4;

__device__ inline unsigned short f2bf(float f) {
  unsigned u = __builtin_bit_cast(unsigned, f);
  u += 0x7FFFu + ((u >> 16) & 1u);
  return (unsigned short)(u >> 16);
}

// A&S 7.1.26 erf approximation, |err| <= 1.5e-7, branchless.
__device__ inline float erf_fast(float x) {
  float ax = fabsf(x);
  float t = 1.0f / (1.0f + 0.3275911f * ax);
  float y = t * (0.254829592f +
           t * (-0.284496736f +
           t * (1.421413741f +
           t * (-1.453152027f +
           t * 1.061405429f))));
  float e = __expf(-ax * ax);
  float r = 1.0f - y * e;
  return copysignf(r, x);
}

// async global->LDS, 16B per lane, wave-uniform LDS base + lane*16
__device__ inline void gload_lds16(const void* g, void* l) {
  __builtin_amdgcn_global_load_lds(
      (const __attribute__((address_space(1))) unsigned int*)g,
      (__attribute__((address_space(3))) unsigned int*)l, 16, 0, 0);
}

// ---------------- X f32 -> bf16 ----------------
__global__ __launch_bounds__(256) void convert_x(const float* __restrict__ X,
                                                 unsigned short* __restrict__ Xb) {
  size_t i = ((size_t)blockIdx.x * 256 + threadIdx.x) * 8;
  f4 v0 = *(const f4*)&X[i];
  f4 v1 = *(const f4*)&X[i + 4];
  sh8 o;
  o[0] = (short)f2bf(v0[0]); o[1] = (short)f2bf(v0[1]);
  o[2] = (short)f2bf(v0[2]); o[3] = (short)f2bf(v0[3]);
  o[4] = (short)f2bf(v1[0]); o[5] = (short)f2bf(v1[1]);
  o[6] = (short)f2bf(v1[2]); o[7] = (short)f2bf(v1[3]);
  *(sh8*)&Xb[i] = o;
}

// ---------------- mean over T, partial sums ----------------
__global__ __launch_bounds__(256) void mean_partial(const float* __restrict__ X,
                                                    float* __restrict__ partial) {
  int tc = blockIdx.x, b = blockIdx.y, t = threadIdx.x;
  float s0 = 0.f, s1 = 0.f, s2 = 0.f, s3 = 0.f;
  const float* base = X + (size_t)b * TT * HH + (size_t)tc * 128 * HH;
  for (int tt = 0; tt < 128; tt++) {
    const float* r = base + (size_t)tt * HH;
    s0 += r[t];
    s1 += r[t + 256];
    s2 += r[t + 512];
    s3 += r[t + 768];
  }
  float* o = partial + ((size_t)b * 16 + tc) * HH;
  o[t] = s0; o[t + 256] = s1; o[t + 512] = s2; o[t + 768] = s3;
}

// ---------------- gating: logits -> softmax -> top2 -> routing ----------------
__global__ __launch_bounds__(256) void gating_kernel(const float* __restrict__ partial,
                                                     const float* __restrict__ gw,
                                                     int* __restrict__ re,
                                                     float* __restrict__ rw) {
  int b = blockIdx.x, t = threadIdx.x;
  float acc[EE];
#pragma unroll
  for (int e = 0; e < EE; e++) acc[e] = 0.f;
  for (int jj = 0; jj < 4; jj++) {
    int h = t + jj * 256;
    float s = 0.f;
    for (int tc = 0; tc < 16; tc++) s += partial[((size_t)b * 16 + tc) * HH + h];
    s *= (1.0f / (float)TT);
#pragma unroll
    for (int e = 0; e < EE; e++) acc[e] += s * gw[h * EE + e];
  }
#pragma unroll
  for (int off = 32; off >= 1; off >>= 1) {
#pragma unroll
    for (int e = 0; e < EE; e++) acc[e] += __shfl_down(acc[e], off);
  }
  __shared__ float red[4][EE];
  if ((t & 63) == 0) {
#pragma unroll
    for (int e = 0; e < EE; e++) red[t >> 6][e] = acc[e];
  }
  __syncthreads();
  if (t == 0) {
    float lg[EE];
#pragma unroll
    for (int e = 0; e < EE; e++) lg[e] = red[0][e] + red[1][e] + red[2][e] + red[3][e];
    float mx = lg[0];
#pragma unroll
    for (int e = 1; e < EE; e++) mx = fmaxf(mx, lg[e]);
    float p[EE]; float s = 0.f;
#pragma unroll
    for (int e = 0; e < EE; e++) { p[e] = expf(lg[e] - mx); s += p[e]; }
#pragma unroll
    for (int e = 0; e < EE; e++) p[e] /= s;
    int i1 = 0;
#pragma unroll
    for (int e = 1; e < EE; e++) if (p[e] > p[i1]) i1 = e;  // first index wins ties
    int i2 = -1;
#pragma unroll
    for (int e = 0; e < EE; e++) {
      if (e == i1) continue;
      if (i2 < 0 || p[e] > p[i2]) i2 = e;
    }
    float den = p[i1] + p[i2];
    re[b * 2 + 0] = i1; rw[b * 2 + 0] = p[i1] / den;
    re[b * 2 + 1] = i2; rw[b * 2 + 1] = p[i2] / den;
  }
}

// ---------------- transpose+convert per-EXPERT weights: W[e][K][N] f32 -> Wt[e][N][K] bf16
__global__ __launch_bounds__(256) void transposeE(const float* __restrict__ W,
                                                  unsigned short* __restrict__ Wt,
                                                  const int* __restrict__ re,
                                                  int K, int N) {
  int e = blockIdx.z;
  bool u = false;
#pragma unroll
  for (int p = 0; p < 16; p++) u = u || (re[p] == e);
  if (!u) return;

  __shared__ float tile[64][65];
  int kb = blockIdx.x, nb = blockIdx.y;
  const float* src = W + (size_t)e * K * N + (size_t)(kb * 64) * N + nb * 64;
  int t = threadIdx.x;
#pragma unroll
  for (int pass = 0; pass < 4; pass++) {
    int r = (t >> 4) + pass * 16;
    int c = (t & 15) * 4;
    *(f4*)&tile[r][c] = *(const f4*)&src[(size_t)r * N + c];
  }
  __syncthreads();
#pragma unroll
  for (int pass = 0; pass < 2; pass++) {
    int idx = (t + pass * 256) * 8;
    int nl = idx >> 6, k0 = idx & 63;
    sh8 o;
#pragma unroll
    for (int j = 0; j < 8; j++) o[j] = (short)f2bf(tile[k0 + j][nl]);
    *(sh8*)&Wt[(size_t)e * N * K + (size_t)(nb * 64 + nl) * K + kb * 64 + k0] = o;
  }
}

// ================= 256x256 8-phase counted-vmcnt GEMM (T1+T2+T3+T4+T5) =================
// MODE 0: hmid[pair] = rw * gelu(X[b] @ w1t[e]^T + b1[e])   (bf16 out, LDS-staged epilogue)
// MODE 1: out[b] = hmid[2b]|hmid[2b+1] (K-concat) @ w2t^T + weighted b2   (f32 out)
// LDS 128KB: A[2][256][64] + B[2][256][64] bf16, XOR swizzle byte ^= (row&7)<<4
// applied as inverse-swizzled GLOBAL SOURCE (gload_lds dest stays linear) + swizzled ds_read.
// R6: all LDS reads = precomputed per-lane base + compile-time offset (folds into
// ds_read offset: immediate); stage loads = precomputed per-lane global element
// offsets + kt*64. Schedule/ledger identical to R5.
// vmcnt ledger: prologue 12 issued, vmcnt(4); steady: 4 units/tile-half, vmcnt(4) at
// phases 4/8; peeled tail stages only tile NT-1 q1 and uses vmcnt(0) at phase 4.

#define PHASE(qm, qn, buf, STMT, VM) do {                                          \
    sh8 afr[4][2], bfr[2][2];                                                      \
    _Pragma("unroll")                                                              \
    for (int m4 = 0; m4 < 4; m4++) {                                               \
      afr[m4][0] = *(const sh8*)(pA0 + (buf) * 32768 + (qm) * 8192 + m4 * 2048);   \
      afr[m4][1] = *(const sh8*)(pA1 + (buf) * 32768 + (qm) * 8192 + m4 * 2048);   \
    }                                                                              \
    _Pragma("unroll")                                                              \
    for (int n2 = 0; n2 < 2; n2++) {                                               \
      bfr[n2][0] = *(const sh8*)(pB0 + (buf) * 32768 + (qn) * 4096 + n2 * 2048);   \
      bfr[n2][1] = *(const sh8*)(pB1 + (buf) * 32768 + (qn) * 4096 + n2 * 2048);   \
    }                                                                              \
    STMT;                                                                          \
    __builtin_amdgcn_sched_barrier(0);                                             \
    __builtin_amdgcn_s_barrier();                                                  \
    asm volatile("s_waitcnt lgkmcnt(0)" ::: "memory");                             \
    __builtin_amdgcn_sched_barrier(0);                                             \
    __builtin_amdgcn_s_setprio(1);                                                 \
    _Pragma("unroll")                                                              \
    for (int m4 = 0; m4 < 4; m4++)                                                 \
      _Pragma("unroll")                                                            \
      for (int n2 = 0; n2 < 2; n2++)                                               \
        _Pragma("unroll")                                                          \
        for (int kk = 0; kk < 2; kk++)                                             \
          acc[(qm) * 4 + m4][(qn) * 2 + n2] =                                      \
              __builtin_amdgcn_mfma_f32_16x16x32_bf16(                             \
                  afr[m4][kk], bfr[n2][kk], acc[(qm) * 4 + m4][(qn) * 2 + n2],     \
                  0, 0, 0);                                                        \
    __builtin_amdgcn_s_setprio(0);                                                 \
    if ((VM) == 4) { asm volatile("s_waitcnt vmcnt(4)" ::: "memory"); }            \
    else if ((VM) == 1) { asm volatile("s_waitcnt vmcnt(0)" ::: "memory"); }       \
    __builtin_amdgcn_sched_barrier(0);                                             \
    __builtin_amdgcn_s_barrier();                                                  \
  } while (0)

// stage unit = 2 gload_lds16 per thread (16KB).
// A unit q: rows {q*64 + lrow, 128 + q*64 + lrow}; B unit q: rows {ld*128 + lrB8 + q*32}.
#define STAGE_A(tau, q) do {                                                       \
    int kt_ = ((tau) < NTH) ? (tau) : (tau) - NTH;                                 \
    const unsigned short* ap_ = ((tau) < NTH) ? A0p : A1p;                         \
    int bo_ = ((tau) & 1) * 32768;                                                 \
    gload_lds16(ap_ + oA##q##0 + kt_ * 64, lds + lA + bo_ + (q) * 8192);           \
    gload_lds16(ap_ + oA##q##1 + kt_ * 64, lds + lA + bo_ + (q) * 8192 + 16384);   \
  } while (0)

#define STAGE_B(tau, q) do {                                                       \
    int kt_ = ((tau) < NTH) ? (tau) : (tau) - NTH;                                 \
    const unsigned short* bp_ = ((tau) < NTH) ? B0p : B1p;                         \
    int bo_ = ((tau) & 1) * 32768;                                                 \
    gload_lds16(bp_ + oB##q##0 + kt_ * 64, lds + lB + bo_ + (q) * 4096);           \
    gload_lds16(bp_ + oB##q##1 + kt_ * 64, lds + lB + bo_ + (q) * 4096 + 16384);   \
  } while (0)

template <int MODE>
__global__ __launch_bounds__(512, 1) void gemm8p(
    const unsigned short* __restrict__ XorH,   // MODE0: Xbf ; MODE1: hmid
    const unsigned short* __restrict__ Wt,     // MODE0: w1t ; MODE1: w2t
    const float* __restrict__ bias,            // MODE0: pb1 ; MODE1: pb2
    const int* __restrict__ re,
    const float* __restrict__ rw,
    unsigned short* __restrict__ hmid_out,     // MODE0 out
    float* __restrict__ out) {                 // MODE1 out
  extern __shared__ char lds[];

  constexpr int NT  = (MODE == 0) ? (HH / 64) : (2 * FF / 64);  // 16 / 128
  constexpr int NTH = (MODE == 0) ? NT : (FF / 64);             // 16 / 64

  int P = blockIdx.x;
  int t = threadIdx.x;
  int lane = t & 63, wv = t >> 6;
  int wr = wv >> 2, wc = wv & 3;       // 2M x 4N waves
  int ln = lane & 15, kq = lane >> 4;

  const unsigned short *A0p, *A1p, *B0p, *B1p;
  int lda, ldb;
  int pair = 0, b, e0, e1, mb, nb;
  if constexpr (MODE == 0) {
    pair = (P & 7) * 2 + ((P >> 3) & 1);    // XCD <-> batch (pairs 2b,2b+1 share XCD)
    int idx = P >> 4;
    mb = idx & 7; nb = idx >> 3;            // mb FAST: concurrent gen shares B panels
    b = pair >> 1;
    e0 = re[pair]; e1 = e0;
    A0p = XorH + (size_t)b * TT * HH + (size_t)mb * 256 * HH; A1p = A0p; lda = HH;
    B0p = Wt + (size_t)e0 * FF * HH + (size_t)nb * 256 * HH; B1p = B0p; ldb = HH;
  } else {
    b = P & 7;                               // XCD <-> batch
    int idx = P >> 3;
    nb = idx & 3; mb = idx >> 2;
    e0 = re[2 * b]; e1 = re[2 * b + 1];
    A0p = XorH + (size_t)(2 * b) * TT * FF + (size_t)mb * 256 * FF;
    A1p = A0p + (size_t)TT * FF; lda = FF;
    B0p = Wt + (size_t)e0 * FF * HH + (size_t)nb * 256 * FF;
    B1p = Wt + (size_t)e1 * FF * HH + (size_t)nb * 256 * FF; ldb = FF;
  }

  // -------- precomputed per-lane addressing (loop-invariant) --------
  // global stage offsets (elements): row(q,ld)*ld{a,b} + swizzled col
  int lrow = t >> 3;                         // A stage row lane part (0..63)
  int lrB8 = (t >> 8) * 64 + ((t >> 3) & 31);// B stage row lane part
  int clel = ((t & 7) ^ ((t >> 3) & 7)) * 8; // inverse-swizzled col (elements)
  size_t oA00 = (size_t)(lrow)*lda + clel;        // q0,ld0
  size_t oA01 = (size_t)(128 + lrow) * lda + clel;// q0,ld1
  size_t oA10 = (size_t)(64 + lrow) * lda + clel; // q1,ld0
  size_t oA11 = (size_t)(192 + lrow) * lda + clel;// q1,ld1
  size_t oB00 = (size_t)(lrB8)*ldb + clel;        // q0,ld0
  size_t oB01 = (size_t)(128 + lrB8) * ldb + clel;// q0,ld1
  size_t oB10 = (size_t)(32 + lrB8) * ldb + clel; // q1,ld0
  size_t oB11 = (size_t)(160 + lrB8) * ldb + clel;// q1,ld1
  // LDS stage dest lane bases (bytes)
  int lA = lrow * 128 + (t & 7) * 16;
  int lB = 65536 + lrB8 * 128 + (t & 7) * 16;
  // LDS read lane bases (bytes); row&7 == ln&7 for all fragment rows
  char* pA0 = lds + wr * 16384 + ln * 128 + ((kq ^ (ln & 7)) * 16);
  char* pA1 = lds + wr * 16384 + ln * 128 + (((4 + kq) ^ (ln & 7)) * 16);
  char* pB0 = lds + 65536 + wc * 8192 + ln * 128 + ((kq ^ (ln & 7)) * 16);
  char* pB1 = lds + 65536 + wc * 8192 + ln * 128 + (((4 + kq) ^ (ln & 7)) * 16);

  f32x4 acc[8][4];
#pragma unroll
  for (int m = 0; m < 8; m++)
#pragma unroll
    for (int n = 0; n < 4; n++) acc[m][n] = (f32x4){0.f, 0.f, 0.f, 0.f};

  // Prologue: tile0 fully (4 units), tile1 q0 (2 units). vmcnt(4)=2 units pending.
  STAGE_A(0, 0); STAGE_B(0, 0); STAGE_A(0, 1); STAGE_B(0, 1);
  STAGE_A(1, 0); STAGE_B(1, 0);
  asm volatile("s_waitcnt vmcnt(4)" ::: "memory");
  __builtin_amdgcn_sched_barrier(0);
  __builtin_amdgcn_s_barrier();

  int T = 0;
  for (; T + 2 < NT; T += 2) {            // steady: T = 0 .. NT-4
    PHASE(0, 0, 0, { STAGE_A(T + 1, 1); }, 0);
    PHASE(0, 1, 0, { STAGE_B(T + 1, 1); }, 0);
    PHASE(1, 0, 0, { STAGE_A(T + 2, 0); }, 0);
    PHASE(1, 1, 0, { STAGE_B(T + 2, 0); }, 4);   // vmcnt(4): tile T+1 complete
    PHASE(0, 0, 1, { STAGE_A(T + 2, 1); }, 0);
    PHASE(0, 1, 1, { STAGE_B(T + 2, 1); }, 0);
    PHASE(1, 0, 1, { STAGE_A(T + 3, 0); }, 0);
    PHASE(1, 1, 1, { STAGE_B(T + 3, 0); }, 4);   // vmcnt(4): tile T+2 complete
  }
  // Peeled tail: T == NT-2. Only tile NT-1 q1 remains to stage.
  PHASE(0, 0, 0, { STAGE_A(T + 1, 1); }, 0);
  PHASE(0, 1, 0, { STAGE_B(T + 1, 1); }, 0);
  PHASE(1, 0, 0, {}, 0);
  PHASE(1, 1, 0, {}, 1);                        // vmcnt(0): tile NT-1 FULLY staged
  PHASE(0, 0, 1, {}, 0);
  PHASE(0, 1, 1, {}, 0);
  PHASE(1, 0, 1, {}, 0);
  PHASE(1, 1, 1, {}, 0);

  // Epilogue
  if constexpr (MODE == 0) {
    float wgt = rw[pair];
    unsigned short* Cout = hmid_out + (size_t)pair * TT * FF;
    float bbv[4];
#pragma unroll
    for (int nn = 0; nn < 4; nn++)
      bbv[nn] = bias[(size_t)e0 * FF + nb * 256 + wc * 64 + nn * 16 + ln];
    // LDS-staged packed store: K-loop LDS (128KB) is dead; 256x256 bf16 tile = 128KB.
    // value(r,c) at lds byte r*512 + ((c*2) ^ (((r>>2)&7)<<4)); bijective per row.
    __syncthreads();
#pragma unroll
    for (int mm = 0; mm < 8; mm++) {
#pragma unroll
      for (int nn = 0; nn < 4; nn++) {
        int c2 = (wc * 64 + nn * 16 + ln) * 2;
#pragma unroll
        for (int j = 0; j < 4; j++) {
          int r = wr * 128 + mm * 16 + kq * 4 + j;
          float v = acc[mm][nn][j] + bbv[nn];
          float g = 0.5f * v * (1.0f + erf_fast(v * 0.70710678118654752f));
          *(unsigned short*)(lds + r * 512 + (c2 ^ (((r >> 2) & 7) << 4))) =
              f2bf(wgt * g);
        }
      }
    }
    __syncthreads();
#pragma unroll
    for (int i = 0; i < 16; i++) {
      int r = wv * 32 + i * 2 + (lane >> 5);
      int ci = lane & 31;
      sh8 v = *(const sh8*)(lds + r * 512 + ((ci ^ ((r >> 2) & 7)) << 4));
      *(sh8*)&Cout[(size_t)(mb * 256 + r) * FF + nb * 256 + ci * 8] = v;
    }
  } else {
    float w0 = rw[2 * b], w1v = rw[2 * b + 1];
#pragma unroll
    for (int nn = 0; nn < 4; nn++) {
      int col = nb * 256 + wc * 64 + nn * 16 + ln;
      float bv = w0 * bias[(size_t)e0 * HH + col] + w1v * bias[(size_t)e1 * HH + col];
#pragma unroll
      for (int mm = 0; mm < 8; mm++) {
#pragma unroll
        for (int j = 0; j < 4; j++) {
          int row = mb * 256 + wr * 128 + mm * 16 + kq * 4 + j;
          out[(size_t)b * TT * HH + (size_t)row * HH + col] = acc[mm][nn][j] + bv;
        }
      }
    }
  }
}

extern "C" void kernel_launch(void* const* d_in, const int* in_sizes, int n_in,
                              void* d_out, int out_size, void* d_ws, size_t ws_size,
                              hipStream_t stream) {
  const float* X  = (const float*)d_in[0];
  const float* gw = (const float*)d_in[1];
  const float* w1 = (const float*)d_in[2];
  const float* pb1 = (const float*)d_in[3];
  const float* w2 = (const float*)d_in[4];
  const float* pb2 = (const float*)d_in[5];
  float* out = (float*)d_out;

  char* ws = (char*)d_ws;
  int* re = (int*)ws;                     // 16 ints
  float* rw = (float*)(ws + 64);          // 16 floats
  float* partial = (float*)(ws + 256);    // [B][16][H] f32 = 512KB
  unsigned short* Xbf = (unsigned short*)(ws + 256 + 524288);  // [B][T][H] bf16 = 32MB
  const size_t fixed = 256 + 524288 + (size_t)BB * TT * HH * 2;

  unsigned short* w1t = (unsigned short*)(ws + fixed);                          // 64MB
  unsigned short* w2t = (unsigned short*)(ws + fixed + (size_t)EE * HH * FF * 2);
  unsigned short* hmid = (unsigned short*)(ws + fixed + (size_t)2 * EE * HH * FF * 2); // 256MB

  hipFuncSetAttribute((const void*)gemm8p<0>,
                      hipFuncAttributeMaxDynamicSharedMemorySize, 131072);
  hipFuncSetAttribute((const void*)gemm8p<1>,
                      hipFuncAttributeMaxDynamicSharedMemorySize, 131072);

  convert_x<<<8192, 256, 0, stream>>>(X, Xbf);
  mean_partial<<<dim3(16, BB), 256, 0, stream>>>(X, partial);
  gating_kernel<<<BB, 256, 0, stream>>>(partial, gw, re, rw);

  transposeE<<<dim3(HH / 64, FF / 64, EE), 256, 0, stream>>>(w1, w1t, re, HH, FF);
  transposeE<<<dim3(FF / 64, HH / 64, EE), 256, 0, stream>>>(w2, w2t, re, FF, HH);

  gemm8p<0><<<2048, 512, 131072, stream>>>(Xbf, w1t, pb1, re, rw, hmid, nullptr);
  gemm8p<1><<<256, 512, 131072, stream>>>(hmid, w2t, pb2, re, rw, nullptr, out);
}

// Round 7
// 683.211 us; speedup vs baseline: 1.7971x; 1.0601x over previous
//
#include <hip/hip_runtime.h>
#include <hip/hip_bf16.h>
#include <math.h>

// Problem constants
#define BB 8
#define TT 2048
#define HH 1024
#define FF 4096
#define EE 8

typedef __attribute__((ext_vector_type(8))) short sh8;   // 8 bf16 (4 VGPRs)
typedef __attribute__((ext_vector_type(4))) float f32x4; // MFMA acc
typedef __attribute__((ext_vector_type(4))) float f4;

__device__ inline unsigned short f2bf(float f) {
  unsigned u = __builtin_bit_cast(unsigned, f);
  u += 0x7FFFu + ((u >> 16) & 1u);
  return (unsigned short)(u >> 16);
}

// A&S 7.1.26 erf approximation, |err| <= 1.5e-7, branchless.
__device__ inline float erf_fast(float x) {
  float ax = fabsf(x);
  float t = 1.0f / (1.0f + 0.3275911f * ax);
  float y = t * (0.254829592f +
           t * (-0.284496736f +
           t * (1.421413741f +
           t * (-1.453152027f +
           t * 1.061405429f))));
  float e = __expf(-ax * ax);
  float r = 1.0f - y * e;
  return copysignf(r, x);
}

// async global->LDS, 16B per lane, wave-uniform LDS base + lane*16
__device__ inline void gload_lds16(const void* g, void* l) {
  __builtin_amdgcn_global_load_lds(
      (const __attribute__((address_space(1))) unsigned int*)g,
      (__attribute__((address_space(3))) unsigned int*)l, 16, 0, 0);
}

// ---------------- X f32 -> bf16 ----------------
__global__ __launch_bounds__(256) void convert_x(const float* __restrict__ X,
                                                 unsigned short* __restrict__ Xb) {
  size_t i = ((size_t)blockIdx.x * 256 + threadIdx.x) * 8;
  f4 v0 = *(const f4*)&X[i];
  f4 v1 = *(const f4*)&X[i + 4];
  sh8 o;
  o[0] = (short)f2bf(v0[0]); o[1] = (short)f2bf(v0[1]);
  o[2] = (short)f2bf(v0[2]); o[3] = (short)f2bf(v0[3]);
  o[4] = (short)f2bf(v1[0]); o[5] = (short)f2bf(v1[1]);
  o[6] = (short)f2bf(v1[2]); o[7] = (short)f2bf(v1[3]);
  *(sh8*)&Xb[i] = o;
}

// ---------------- mean over T, partial sums ----------------
__global__ __launch_bounds__(256) void mean_partial(const float* __restrict__ X,
                                                    float* __restrict__ partial) {
  int tc = blockIdx.x, b = blockIdx.y, t = threadIdx.x;
  float s0 = 0.f, s1 = 0.f, s2 = 0.f, s3 = 0.f;
  const float* base = X + (size_t)b * TT * HH + (size_t)tc * 128 * HH;
  for (int tt = 0; tt < 128; tt++) {
    const float* r = base + (size_t)tt * HH;
    s0 += r[t];
    s1 += r[t + 256];
    s2 += r[t + 512];
    s3 += r[t + 768];
  }
  float* o = partial + ((size_t)b * 16 + tc) * HH;
  o[t] = s0; o[t + 256] = s1; o[t + 512] = s2; o[t + 768] = s3;
}

// ---------------- gating: logits -> softmax -> top2 -> routing ----------------
__global__ __launch_bounds__(256) void gating_kernel(const float* __restrict__ partial,
                                                     const float* __restrict__ gw,
                                                     int* __restrict__ re,
                                                     float* __restrict__ rw) {
  int b = blockIdx.x, t = threadIdx.x;
  float acc[EE];
#pragma unroll
  for (int e = 0; e < EE; e++) acc[e] = 0.f;
  for (int jj = 0; jj < 4; jj++) {
    int h = t + jj * 256;
    float s = 0.f;
    for (int tc = 0; tc < 16; tc++) s += partial[((size_t)b * 16 + tc) * HH + h];
    s *= (1.0f / (float)TT);
#pragma unroll
    for (int e = 0; e < EE; e++) acc[e] += s * gw[h * EE + e];
  }
#pragma unroll
  for (int off = 32; off >= 1; off >>= 1) {
#pragma unroll
    for (int e = 0; e < EE; e++) acc[e] += __shfl_down(acc[e], off);
  }
  __shared__ float red[4][EE];
  if ((t & 63) == 0) {
#pragma unroll
    for (int e = 0; e < EE; e++) red[t >> 6][e] = acc[e];
  }
  __syncthreads();
  if (t == 0) {
    float lg[EE];
#pragma unroll
    for (int e = 0; e < EE; e++) lg[e] = red[0][e] + red[1][e] + red[2][e] + red[3][e];
    float mx = lg[0];
#pragma unroll
    for (int e = 1; e < EE; e++) mx = fmaxf(mx, lg[e]);
    float p[EE]; float s = 0.f;
#pragma unroll
    for (int e = 0; e < EE; e++) { p[e] = expf(lg[e] - mx); s += p[e]; }
#pragma unroll
    for (int e = 0; e < EE; e++) p[e] /= s;
    int i1 = 0;
#pragma unroll
    for (int e = 1; e < EE; e++) if (p[e] > p[i1]) i1 = e;  // first index wins ties
    int i2 = -1;
#pragma unroll
    for (int e = 0; e < EE; e++) {
      if (e == i1) continue;
      if (i2 < 0 || p[e] > p[i2]) i2 = e;
    }
    float den = p[i1] + p[i2];
    re[b * 2 + 0] = i1; rw[b * 2 + 0] = p[i1] / den;
    re[b * 2 + 1] = i2; rw[b * 2 + 1] = p[i2] / den;
  }
}

// ---------------- transpose+convert per-EXPERT weights: W[e][K][N] f32 -> Wt[e][N][K] bf16
__global__ __launch_bounds__(256) void transposeE(const float* __restrict__ W,
                                                  unsigned short* __restrict__ Wt,
                                                  const int* __restrict__ re,
                                                  int K, int N) {
  int e = blockIdx.z;
  bool u = false;
#pragma unroll
  for (int p = 0; p < 16; p++) u = u || (re[p] == e);
  if (!u) return;

  __shared__ float tile[64][65];
  int kb = blockIdx.x, nb = blockIdx.y;
  const float* src = W + (size_t)e * K * N + (size_t)(kb * 64) * N + nb * 64;
  int t = threadIdx.x;
#pragma unroll
  for (int pass = 0; pass < 4; pass++) {
    int r = (t >> 4) + pass * 16;
    int c = (t & 15) * 4;
    *(f4*)&tile[r][c] = *(const f4*)&src[(size_t)r * N + c];
  }
  __syncthreads();
#pragma unroll
  for (int pass = 0; pass < 2; pass++) {
    int idx = (t + pass * 256) * 8;
    int nl = idx >> 6, k0 = idx & 63;
    sh8 o;
#pragma unroll
    for (int j = 0; j < 8; j++) o[j] = (short)f2bf(tile[k0 + j][nl]);
    *(sh8*)&Wt[(size_t)e * N * K + (size_t)(nb * 64 + nl) * K + kb * 64 + k0] = o;
  }
}

// ================= 256x256 8-phase counted-vmcnt GEMM (T1+T2+T3+T4+T5) =================
// MODE 0: hmid[pair] = rw * gelu(X[b] @ w1t[e]^T + b1[e])   (bf16 out, LDS-staged epilogue)
// MODE 1: out[b] = hmid[2b]|hmid[2b+1] (K-concat) @ w2t^T + weighted b2   (f32 out)
// LDS 128KB: A[2][256][64] + B[2][256][64] bf16, XOR swizzle byte ^= (row&7)<<4
// applied as inverse-swizzled GLOBAL SOURCE (gload_lds dest stays linear) + swizzled ds_read.
// R7: register fragment reuse — each fragment ds_read ONCE per tile (24 reads/tile,
// m201-style, was 48): PH1 reads A(qm0)+B(qn0) -> MFMA(0,0); PH2 reads B(qn1) ->
// MFMA(0,1); PH3 reads A(qm1) over Aq -> MFMA(1,1); PH4 no reads -> MFMA(1,0).
// Race-safety identical to R5/R6: q0 rows last read in phases 1-2, restaged phase 3;
// q1 rows last read in phase 3, restaged next-tile phase 1.
// vmcnt ledger (unchanged): prologue 12 issued, vmcnt(4); steady: vmcnt(4) at
// phases 4/8; peeled tail stages only tile NT-1 q1 and uses vmcnt(0) at phase 4.

#define MFMA_CL(qm, qn, BREG)                                                      \
    __builtin_amdgcn_s_setprio(1);                                                 \
    _Pragma("unroll")                                                              \
    for (int m4 = 0; m4 < 4; m4++)                                                 \
      _Pragma("unroll")                                                            \
      for (int n2 = 0; n2 < 2; n2++)                                               \
        _Pragma("unroll")                                                          \
        for (int kk = 0; kk < 2; kk++)                                             \
          acc[(qm) * 4 + m4][(qn) * 2 + n2] =                                      \
              __builtin_amdgcn_mfma_f32_16x16x32_bf16(                             \
                  Aq[m4 * 2 + kk], BREG[n2 * 2 + kk],                              \
                  acc[(qm) * 4 + m4][(qn) * 2 + n2], 0, 0, 0);                     \
    __builtin_amdgcn_s_setprio(0);

#define PH_PRE                                                                     \
    __builtin_amdgcn_sched_barrier(0);                                             \
    __builtin_amdgcn_s_barrier();                                                  \
    asm volatile("s_waitcnt lgkmcnt(0)" ::: "memory");                             \
    __builtin_amdgcn_sched_barrier(0);

#define PH_POST(VM)                                                                \
    if ((VM) == 4) { asm volatile("s_waitcnt vmcnt(4)" ::: "memory"); }            \
    else if ((VM) == 1) { asm volatile("s_waitcnt vmcnt(0)" ::: "memory"); }       \
    __builtin_amdgcn_sched_barrier(0);                                             \
    __builtin_amdgcn_s_barrier();

#define PH1(buf, STMT, VM) do {                                                    \
    _Pragma("unroll")                                                              \
    for (int m4 = 0; m4 < 4; m4++) {                                               \
      Aq[m4 * 2]     = *(const sh8*)(pA0 + (buf) * 32768 + m4 * 2048);             \
      Aq[m4 * 2 + 1] = *(const sh8*)(pA1 + (buf) * 32768 + m4 * 2048);             \
    }                                                                              \
    _Pragma("unroll")                                                              \
    for (int n2 = 0; n2 < 2; n2++) {                                               \
      B0r[n2 * 2]     = *(const sh8*)(pB0 + (buf) * 32768 + n2 * 2048);            \
      B0r[n2 * 2 + 1] = *(const sh8*)(pB1 + (buf) * 32768 + n2 * 2048);            \
    }                                                                              \
    STMT; PH_PRE MFMA_CL(0, 0, B0r) PH_POST(VM) } while (0)

#define PH2(buf, STMT, VM) do {                                                    \
    _Pragma("unroll")                                                              \
    for (int n2 = 0; n2 < 2; n2++) {                                               \
      B1r[n2 * 2]     = *(const sh8*)(pB0 + (buf) * 32768 + 4096 + n2 * 2048);     \
      B1r[n2 * 2 + 1] = *(const sh8*)(pB1 + (buf) * 32768 + 4096 + n2 * 2048);     \
    }                                                                              \
    STMT; PH_PRE MFMA_CL(0, 1, B1r) PH_POST(VM) } while (0)

#define PH3(buf, STMT, VM) do {                                                    \
    _Pragma("unroll")                                                              \
    for (int m4 = 0; m4 < 4; m4++) {                                               \
      Aq[m4 * 2]     = *(const sh8*)(pA0 + (buf) * 32768 + 8192 + m4 * 2048);      \
      Aq[m4 * 2 + 1] = *(const sh8*)(pA1 + (buf) * 32768 + 8192 + m4 * 2048);      \
    }                                                                              \
    STMT; PH_PRE MFMA_CL(1, 1, B1r) PH_POST(VM) } while (0)

#define PH4(buf, STMT, VM) do {                                                    \
    STMT; PH_PRE MFMA_CL(1, 0, B0r) PH_POST(VM) } while (0)

// stage unit = 2 gload_lds16 per thread (16KB).
// A unit q: rows {q*64 + lrow, 128 + q*64 + lrow}; B unit q: rows {ld*128 + lrB8 + q*32}.
#define STAGE_A(tau, q) do {                                                       \
    int kt_ = ((tau) < NTH) ? (tau) : (tau) - NTH;                                 \
    const unsigned short* ap_ = ((tau) < NTH) ? A0p : A1p;                         \
    int bo_ = ((tau) & 1) * 32768;                                                 \
    gload_lds16(ap_ + oA##q##0 + kt_ * 64, lds + lA + bo_ + (q) * 8192);           \
    gload_lds16(ap_ + oA##q##1 + kt_ * 64, lds + lA + bo_ + (q) * 8192 + 16384);   \
  } while (0)

#define STAGE_B(tau, q) do {                                                       \
    int kt_ = ((tau) < NTH) ? (tau) : (tau) - NTH;                                 \
    const unsigned short* bp_ = ((tau) < NTH) ? B0p : B1p;                         \
    int bo_ = ((tau) & 1) * 32768;                                                 \
    gload_lds16(bp_ + oB##q##0 + kt_ * 64, lds + lB + bo_ + (q) * 4096);           \
    gload_lds16(bp_ + oB##q##1 + kt_ * 64, lds + lB + bo_ + (q) * 4096 + 16384);   \
  } while (0)

template <int MODE>
__global__ __launch_bounds__(512, 1) void gemm8p(
    const unsigned short* __restrict__ XorH,   // MODE0: Xbf ; MODE1: hmid
    const unsigned short* __restrict__ Wt,     // MODE0: w1t ; MODE1: w2t
    const float* __restrict__ bias,            // MODE0: pb1 ; MODE1: pb2
    const int* __restrict__ re,
    const float* __restrict__ rw,
    unsigned short* __restrict__ hmid_out,     // MODE0 out
    float* __restrict__ out) {                 // MODE1 out
  extern __shared__ char lds[];

  constexpr int NT  = (MODE == 0) ? (HH / 64) : (2 * FF / 64);  // 16 / 128
  constexpr int NTH = (MODE == 0) ? NT : (FF / 64);             // 16 / 64

  int P = blockIdx.x;
  int t = threadIdx.x;
  int lane = t & 63, wv = t >> 6;
  int wr = wv >> 2, wc = wv & 3;       // 2M x 4N waves
  int ln = lane & 15, kq = lane >> 4;

  const unsigned short *A0p, *A1p, *B0p, *B1p;
  int lda, ldb;
  int pair = 0, b, e0, e1, mb, nb;
  if constexpr (MODE == 0) {
    pair = (P & 7) * 2 + ((P >> 3) & 1);    // XCD <-> batch (pairs 2b,2b+1 share XCD)
    int idx = P >> 4;
    mb = idx & 7; nb = idx >> 3;            // mb FAST: concurrent gen shares B panels
    b = pair >> 1;
    e0 = re[pair]; e1 = e0;
    A0p = XorH + (size_t)b * TT * HH + (size_t)mb * 256 * HH; A1p = A0p; lda = HH;
    B0p = Wt + (size_t)e0 * FF * HH + (size_t)nb * 256 * HH; B1p = B0p; ldb = HH;
  } else {
    b = P & 7;                               // XCD <-> batch
    int idx = P >> 3;
    nb = idx & 3; mb = idx >> 2;
    e0 = re[2 * b]; e1 = re[2 * b + 1];
    A0p = XorH + (size_t)(2 * b) * TT * FF + (size_t)mb * 256 * FF;
    A1p = A0p + (size_t)TT * FF; lda = FF;
    B0p = Wt + (size_t)e0 * FF * HH + (size_t)nb * 256 * FF;
    B1p = Wt + (size_t)e1 * FF * HH + (size_t)nb * 256 * FF; ldb = FF;
  }

  // -------- precomputed per-lane addressing (loop-invariant) --------
  int lrow = t >> 3;                         // A stage row lane part (0..63)
  int lrB8 = (t >> 8) * 64 + ((t >> 3) & 31);// B stage row lane part
  int clel = ((t & 7) ^ ((t >> 3) & 7)) * 8; // inverse-swizzled col (elements)
  size_t oA00 = (size_t)(lrow)*lda + clel;        // q0,ld0
  size_t oA01 = (size_t)(128 + lrow) * lda + clel;// q0,ld1
  size_t oA10 = (size_t)(64 + lrow) * lda + clel; // q1,ld0
  size_t oA11 = (size_t)(192 + lrow) * lda + clel;// q1,ld1
  size_t oB00 = (size_t)(lrB8)*ldb + clel;        // q0,ld0
  size_t oB01 = (size_t)(128 + lrB8) * ldb + clel;// q0,ld1
  size_t oB10 = (size_t)(32 + lrB8) * ldb + clel; // q1,ld0
  size_t oB11 = (size_t)(160 + lrB8) * ldb + clel;// q1,ld1
  // LDS stage dest lane bases (bytes)
  int lA = lrow * 128 + (t & 7) * 16;
  int lB = 65536 + lrB8 * 128 + (t & 7) * 16;
  // LDS read lane bases (bytes); row&7 == ln&7 for all fragment rows
  char* pA0 = lds + wr * 16384 + ln * 128 + ((kq ^ (ln & 7)) * 16);
  char* pA1 = lds + wr * 16384 + ln * 128 + (((4 + kq) ^ (ln & 7)) * 16);
  char* pB0 = lds + 65536 + wc * 8192 + ln * 128 + ((kq ^ (ln & 7)) * 16);
  char* pB1 = lds + 65536 + wc * 8192 + ln * 128 + (((4 + kq) ^ (ln & 7)) * 16);

  f32x4 acc[8][4];
#pragma unroll
  for (int m = 0; m < 8; m++)
#pragma unroll
    for (int n = 0; n < 4; n++) acc[m][n] = (f32x4){0.f, 0.f, 0.f, 0.f};

  sh8 Aq[8], B0r[4], B1r[4];

  // Prologue: tile0 fully (4 units), tile1 q0 (2 units). vmcnt(4)=2 units pending.
  STAGE_A(0, 0); STAGE_B(0, 0); STAGE_A(0, 1); STAGE_B(0, 1);
  STAGE_A(1, 0); STAGE_B(1, 0);
  asm volatile("s_waitcnt vmcnt(4)" ::: "memory");
  __builtin_amdgcn_sched_barrier(0);
  __builtin_amdgcn_s_barrier();

  int T = 0;
  for (; T + 2 < NT; T += 2) {            // steady: processes tiles T (buf0), T+1 (buf1)
    PH1(0, { STAGE_A(T + 1, 1); }, 0);
    PH2(0, { STAGE_B(T + 1, 1); }, 0);
    PH3(0, { STAGE_A(T + 2, 0); }, 0);
    PH4(0, { STAGE_B(T + 2, 0); }, 4);    // vmcnt(4): tile T+1 complete
    PH1(1, { STAGE_A(T + 2, 1); }, 0);
    PH2(1, { STAGE_B(T + 2, 1); }, 0);
    PH3(1, { STAGE_A(T + 3, 0); }, 0);
    PH4(1, { STAGE_B(T + 3, 0); }, 4);    // vmcnt(4): tile T+2 complete
  }
  // Peeled tail: T == NT-2. Only tile NT-1 q1 remains to stage.
  PH1(0, { STAGE_A(T + 1, 1); }, 0);
  PH2(0, { STAGE_B(T + 1, 1); }, 0);
  PH3(0, {}, 0);
  PH4(0, {}, 1);                          // vmcnt(0): tile NT-1 FULLY staged
  PH1(1, {}, 0);
  PH2(1, {}, 0);
  PH3(1, {}, 0);
  PH4(1, {}, 0);

  // Epilogue
  if constexpr (MODE == 0) {
    float wgt = rw[pair];
    unsigned short* Cout = hmid_out + (size_t)pair * TT * FF;
    float bbv[4];
#pragma unroll
    for (int nn = 0; nn < 4; nn++)
      bbv[nn] = bias[(size_t)e0 * FF + nb * 256 + wc * 64 + nn * 16 + ln];
    // LDS-staged packed store: K-loop LDS (128KB) is dead; 256x256 bf16 tile = 128KB.
    // value(r,c) at lds byte r*512 + ((c*2) ^ (((r>>2)&7)<<4)); bijective per row.
    __syncthreads();
#pragma unroll
    for (int mm = 0; mm < 8; mm++) {
#pragma unroll
      for (int nn = 0; nn < 4; nn++) {
        int c2 = (wc * 64 + nn * 16 + ln) * 2;
#pragma unroll
        for (int j = 0; j < 4; j++) {
          int r = wr * 128 + mm * 16 + kq * 4 + j;
          float v = acc[mm][nn][j] + bbv[nn];
          float g = 0.5f * v * (1.0f + erf_fast(v * 0.70710678118654752f));
          *(unsigned short*)(lds + r * 512 + (c2 ^ (((r >> 2) & 7) << 4))) =
              f2bf(wgt * g);
        }
      }
    }
    __syncthreads();
#pragma unroll
    for (int i = 0; i < 16; i++) {
      int r = wv * 32 + i * 2 + (lane >> 5);
      int ci = lane & 31;
      sh8 v = *(const sh8*)(lds + r * 512 + ((ci ^ ((r >> 2) & 7)) << 4));
      *(sh8*)&Cout[(size_t)(mb * 256 + r) * FF + nb * 256 + ci * 8] = v;
    }
  } else {
    float w0 = rw[2 * b], w1v = rw[2 * b + 1];
#pragma unroll
    for (int nn = 0; nn < 4; nn++) {
      int col = nb * 256 + wc * 64 + nn * 16 + ln;
      float bv = w0 * bias[(size_t)e0 * HH + col] + w1v * bias[(size_t)e1 * HH + col];
#pragma unroll
      for (int mm = 0; mm < 8; mm++) {
#pragma unroll
        for (int j = 0; j < 4; j++) {
          int row = mb * 256 + wr * 128 + mm * 16 + kq * 4 + j;
          out[(size_t)b * TT * HH + (size_t)row * HH + col] = acc[mm][nn][j] + bv;
        }
      }
    }
  }
}

extern "C" void kernel_launch(void* const* d_in, const int* in_sizes, int n_in,
                              void* d_out, int out_size, void* d_ws, size_t ws_size,
                              hipStream_t stream) {
  const float* X  = (const float*)d_in[0];
  const float* gw = (const float*)d_in[1];
  const float* w1 = (const float*)d_in[2];
  const float* pb1 = (const float*)d_in[3];
  const float* w2 = (const float*)d_in[4];
  const float* pb2 = (const float*)d_in[5];
  float* out = (float*)d_out;

  char* ws = (char*)d_ws;
  int* re = (int*)ws;                     // 16 ints
  float* rw = (float*)(ws + 64);          // 16 floats
  float* partial = (float*)(ws + 256);    // [B][16][H] f32 = 512KB
  unsigned short* Xbf = (unsigned short*)(ws + 256 + 524288);  // [B][T][H] bf16 = 32MB
  const size_t fixed = 256 + 524288 + (size_t)BB * TT * HH * 2;

  unsigned short* w1t = (unsigned short*)(ws + fixed);                          // 64MB
  unsigned short* w2t = (unsigned short*)(ws + fixed + (size_t)EE * HH * FF * 2);
  unsigned short* hmid = (unsigned short*)(ws + fixed + (size_t)2 * EE * HH * FF * 2); // 256MB

  hipFuncSetAttribute((const void*)gemm8p<0>,
                      hipFuncAttributeMaxDynamicSharedMemorySize, 131072);
  hipFuncSetAttribute((const void*)gemm8p<1>,
                      hipFuncAttributeMaxDynamicSharedMemorySize, 131072);

  convert_x<<<8192, 256, 0, stream>>>(X, Xbf);
  mean_partial<<<dim3(16, BB), 256, 0, stream>>>(X, partial);
  gating_kernel<<<BB, 256, 0, stream>>>(partial, gw, re, rw);

  transposeE<<<dim3(HH / 64, FF / 64, EE), 256, 0, stream>>>(w1, w1t, re, HH, FF);
  transposeE<<<dim3(FF / 64, HH / 64, EE), 256, 0, stream>>>(w2, w2t, re, FF, HH);

  gemm8p<0><<<2048, 512, 131072, stream>>>(Xbf, w1t, pb1, re, rw, hmid, nullptr);
  gemm8p<1><<<256, 512, 131072, stream>>>(hmid, w2t, pb2, re, rw, nullptr, out);
}

// Round 8
// 641.499 us; speedup vs baseline: 1.9140x; 1.0650x over previous
//
#include <hip/hip_runtime.h>
#include <hip/hip_bf16.h>
#include <math.h>

// Problem constants
#define BB 8
#define TT 2048
#define HH 1024
#define FF 4096
#define EE 8

typedef __attribute__((ext_vector_type(8))) short sh8;   // 8 bf16 (4 VGPRs)
typedef __attribute__((ext_vector_type(4))) short sh4;   // 4 bf16 (8B)
typedef __attribute__((ext_vector_type(4))) float f32x4; // MFMA acc
typedef __attribute__((ext_vector_type(4))) float f4;

__device__ inline unsigned short f2bf(float f) {
  unsigned u = __builtin_bit_cast(unsigned, f);
  u += 0x7FFFu + ((u >> 16) & 1u);
  return (unsigned short)(u >> 16);
}

// A&S 7.1.26 erf approximation, |err| <= 1.5e-7, branchless.
__device__ inline float erf_fast(float x) {
  float ax = fabsf(x);
  float t = 1.0f / (1.0f + 0.3275911f * ax);
  float y = t * (0.254829592f +
           t * (-0.284496736f +
           t * (1.421413741f +
           t * (-1.453152027f +
           t * 1.061405429f))));
  float e = __expf(-ax * ax);
  float r = 1.0f - y * e;
  return copysignf(r, x);
}

// async global->LDS, 16B per lane, wave-uniform LDS base + lane*16
__device__ inline void gload_lds16(const void* g, void* l) {
  __builtin_amdgcn_global_load_lds(
      (const __attribute__((address_space(1))) unsigned int*)g,
      (__attribute__((address_space(3))) unsigned int*)l, 16, 0, 0);
}

// ---------------- fused: X f32 -> bf16 AND per-chunk column partial sums ----------------
__global__ __launch_bounds__(256) void prep(const float* __restrict__ X,
                                            unsigned short* __restrict__ Xb,
                                            float* __restrict__ partial) {
  int tc = blockIdx.x, b = blockIdx.y, t = threadIdx.x;
  const float* src = X + ((size_t)b * TT + (size_t)tc * 128) * HH;
  unsigned short* dst = Xb + ((size_t)b * TT + (size_t)tc * 128) * HH;
  f4 s = {0.f, 0.f, 0.f, 0.f};
  for (int r = 0; r < 128; ++r) {
    f4 v = *(const f4*)&src[(size_t)r * HH + t * 4];
    s[0] += v[0]; s[1] += v[1]; s[2] += v[2]; s[3] += v[3];
    sh4 o;
    o[0] = (short)f2bf(v[0]); o[1] = (short)f2bf(v[1]);
    o[2] = (short)f2bf(v[2]); o[3] = (short)f2bf(v[3]);
    *(sh4*)&dst[(size_t)r * HH + t * 4] = o;
  }
  *(f4*)&partial[((size_t)b * 16 + tc) * HH + t * 4] = s;
}

// ---------------- gating: logits -> softmax -> top2 -> routing ----------------
__global__ __launch_bounds__(256) void gating_kernel(const float* __restrict__ partial,
                                                     const float* __restrict__ gw,
                                                     int* __restrict__ re,
                                                     float* __restrict__ rw) {
  int b = blockIdx.x, t = threadIdx.x;
  float acc[EE];
#pragma unroll
  for (int e = 0; e < EE; e++) acc[e] = 0.f;
  for (int jj = 0; jj < 4; jj++) {
    int h = t + jj * 256;
    float s = 0.f;
    for (int tc = 0; tc < 16; tc++) s += partial[((size_t)b * 16 + tc) * HH + h];
    s *= (1.0f / (float)TT);
#pragma unroll
    for (int e = 0; e < EE; e++) acc[e] += s * gw[h * EE + e];
  }
#pragma unroll
  for (int off = 32; off >= 1; off >>= 1) {
#pragma unroll
    for (int e = 0; e < EE; e++) acc[e] += __shfl_down(acc[e], off);
  }
  __shared__ float red[4][EE];
  if ((t & 63) == 0) {
#pragma unroll
    for (int e = 0; e < EE; e++) red[t >> 6][e] = acc[e];
  }
  __syncthreads();
  if (t == 0) {
    float lg[EE];
#pragma unroll
    for (int e = 0; e < EE; e++) lg[e] = red[0][e] + red[1][e] + red[2][e] + red[3][e];
    float mx = lg[0];
#pragma unroll
    for (int e = 1; e < EE; e++) mx = fmaxf(mx, lg[e]);
    float p[EE]; float s = 0.f;
#pragma unroll
    for (int e = 0; e < EE; e++) { p[e] = expf(lg[e] - mx); s += p[e]; }
#pragma unroll
    for (int e = 0; e < EE; e++) p[e] /= s;
    int i1 = 0;
#pragma unroll
    for (int e = 1; e < EE; e++) if (p[e] > p[i1]) i1 = e;  // first index wins ties
    int i2 = -1;
#pragma unroll
    for (int e = 0; e < EE; e++) {
      if (e == i1) continue;
      if (i2 < 0 || p[e] > p[i2]) i2 = e;
    }
    float den = p[i1] + p[i2];
    re[b * 2 + 0] = i1; rw[b * 2 + 0] = p[i1] / den;
    re[b * 2 + 1] = i2; rw[b * 2 + 1] = p[i2] / den;
  }
}

// ---------------- transpose+convert per-EXPERT weights: W[e][K][N] f32 -> Wt[e][N][K] bf16
__global__ __launch_bounds__(256) void transposeE(const float* __restrict__ W,
                                                  unsigned short* __restrict__ Wt,
                                                  const int* __restrict__ re,
                                                  int K, int N) {
  int e = blockIdx.z;
  bool u = false;
#pragma unroll
  for (int p = 0; p < 16; p++) u = u || (re[p] == e);
  if (!u) return;

  __shared__ float tile[64][65];
  int kb = blockIdx.x, nb = blockIdx.y;
  const float* src = W + (size_t)e * K * N + (size_t)(kb * 64) * N + nb * 64;
  int t = threadIdx.x;
#pragma unroll
  for (int pass = 0; pass < 4; pass++) {
    int r = (t >> 4) + pass * 16;
    int c = (t & 15) * 4;
    *(f4*)&tile[r][c] = *(const f4*)&src[(size_t)r * N + c];
  }
  __syncthreads();
#pragma unroll
  for (int pass = 0; pass < 2; pass++) {
    int idx = (t + pass * 256) * 8;
    int nl = idx >> 6, k0 = idx & 63;
    sh8 o;
#pragma unroll
    for (int j = 0; j < 8; j++) o[j] = (short)f2bf(tile[k0 + j][nl]);
    *(sh8*)&Wt[(size_t)e * N * K + (size_t)(nb * 64 + nl) * K + kb * 64 + k0] = o;
  }
}

// ================= 256x256 8-phase counted-vmcnt GEMM (T1+T2+T3+T4+T5) =================
// MODE 0 (PERSISTENT, R8): grid 256, block = (pair, mb, nbhalf); loops 8 nb-segments
//   with a CONTINUOUS K-pipeline (tau = 0..127 global; stage pointers cross segment
//   boundaries; single prologue/tail). Per-segment epilogue: bias+gelu+wgt, written
//   to hmid in BLOCK-PERMUTED layout via 128B-coalesced nontemporal stores (no LDS
//   use -> staging stays in flight). A panel (X[b],mb) pinned in L2 across segments.
// MODE 1: out[b] = hmid-pair-concat (K) @ w2t^T + weighted b2. A-staging reads the
//   permuted hmid layout: per-lane fixed offset F + per-tau (kt>>2)*65536+(kt&3)*8192.
// hmid permuted layout (elements, per pair): tile(mb,kb)*65536 + wave(wr*4+wc)*8192 +
//   (mm*16+nn*4+j)*64 + kq*16 + ln   [row r=(wr<<7)|(mm<<4)|(kq<<2)|j, col c=(kb<<8)|
//   (wc<<6)|(nn<<4)|ln] -- ln innermost => 16B source chunks = 8 consecutive cols.
// LDS 128KB: A[2][256][64] + B[2][256][64] bf16, XOR swizzle byte ^= (row&7)<<4 via
//   inverse-swizzled GLOBAL SOURCE + swizzled ds_read. Frags read ONCE per tile (24).
// vmcnt ledger: prologue 12 issued, vmcnt(4); steady vmcnt(4) at phases 4/8; final
//   tail stages only tile NT-1 q1 and uses vmcnt(0) at phase 4. Epilogue stores add
//   to vmcnt; the next vmcnt(4) drains them first (safe, they ack in L2 fast).

#define MFMA_CL(qm, qn, BREG)                                                      \
    __builtin_amdgcn_s_setprio(1);                                                 \
    _Pragma("unroll")                                                              \
    for (int m4 = 0; m4 < 4; m4++)                                                 \
      _Pragma("unroll")                                                            \
      for (int n2 = 0; n2 < 2; n2++)                                               \
        _Pragma("unroll")                                                          \
        for (int kk = 0; kk < 2; kk++)                                             \
          acc[(qm) * 4 + m4][(qn) * 2 + n2] =                                      \
              __builtin_amdgcn_mfma_f32_16x16x32_bf16(                             \
                  Aq[m4 * 2 + kk], BREG[n2 * 2 + kk],                              \
                  acc[(qm) * 4 + m4][(qn) * 2 + n2], 0, 0, 0);                     \
    __builtin_amdgcn_s_setprio(0);

#define PH_PRE                                                                     \
    __builtin_amdgcn_sched_barrier(0);                                             \
    __builtin_amdgcn_s_barrier();                                                  \
    asm volatile("s_waitcnt lgkmcnt(0)" ::: "memory");                             \
    __builtin_amdgcn_sched_barrier(0);

#define PH_POST(VM)                                                                \
    if ((VM) == 4) { asm volatile("s_waitcnt vmcnt(4)" ::: "memory"); }            \
    else if ((VM) == 1) { asm volatile("s_waitcnt vmcnt(0)" ::: "memory"); }       \
    __builtin_amdgcn_sched_barrier(0);                                             \
    __builtin_amdgcn_s_barrier();

#define PH1(buf, STMT, VM) do {                                                    \
    _Pragma("unroll")                                                              \
    for (int m4 = 0; m4 < 4; m4++) {                                               \
      Aq[m4 * 2]     = *(const sh8*)(pA0 + (buf) * 32768 + m4 * 2048);             \
      Aq[m4 * 2 + 1] = *(const sh8*)(pA1 + (buf) * 32768 + m4 * 2048);             \
    }                                                                              \
    _Pragma("unroll")                                                              \
    for (int n2 = 0; n2 < 2; n2++) {                                               \
      B0r[n2 * 2]     = *(const sh8*)(pB0 + (buf) * 32768 + n2 * 2048);            \
      B0r[n2 * 2 + 1] = *(const sh8*)(pB1 + (buf) * 32768 + n2 * 2048);            \
    }                                                                              \
    STMT; PH_PRE MFMA_CL(0, 0, B0r) PH_POST(VM) } while (0)

#define PH2(buf, STMT, VM) do {                                                    \
    _Pragma("unroll")                                                              \
    for (int n2 = 0; n2 < 2; n2++) {                                               \
      B1r[n2 * 2]     = *(const sh8*)(pB0 + (buf) * 32768 + 4096 + n2 * 2048);     \
      B1r[n2 * 2 + 1] = *(const sh8*)(pB1 + (buf) * 32768 + 4096 + n2 * 2048);     \
    }                                                                              \
    STMT; PH_PRE MFMA_CL(0, 1, B1r) PH_POST(VM) } while (0)

#define PH3(buf, STMT, VM) do {                                                    \
    _Pragma("unroll")                                                              \
    for (int m4 = 0; m4 < 4; m4++) {                                               \
      Aq[m4 * 2]     = *(const sh8*)(pA0 + (buf) * 32768 + 8192 + m4 * 2048);      \
      Aq[m4 * 2 + 1] = *(const sh8*)(pA1 + (buf) * 32768 + 8192 + m4 * 2048);      \
    }                                                                              \
    STMT; PH_PRE MFMA_CL(1, 1, B1r) PH_POST(VM) } while (0)

#define PH4(buf, STMT, VM) do {                                                    \
    STMT; PH_PRE MFMA_CL(1, 0, B0r) PH_POST(VM) } while (0)

// stage unit = 2 gload_lds16 per thread (16KB).
#define STAGE_A(tau, q) do {                                                       \
    int bo_ = ((tau) & 1) * 32768;                                                 \
    if constexpr (MODE == 0) {                                                     \
      const unsigned short* ap_ = A0p + ((tau) & 15) * 64;                         \
      gload_lds16(ap_ + oA##q##0, lds + lA + bo_ + (q) * 8192);                    \
      gload_lds16(ap_ + oA##q##1, lds + lA + bo_ + (q) * 8192 + 16384);            \
    } else {                                                                       \
      int kt_ = ((tau) < NTH) ? (tau) : (tau) - NTH;                               \
      const unsigned short* ap_ = (((tau) < NTH) ? H0p : H1p) +                    \
                                  (kt_ >> 2) * 65536 + (kt_ & 3) * 8192;           \
      gload_lds16(ap_ + fA##q##0, lds + lA + bo_ + (q) * 8192);                    \
      gload_lds16(ap_ + fA##q##1, lds + lA + bo_ + (q) * 8192 + 16384);            \
    } } while (0)

#define STAGE_B(tau, q) do {                                                       \
    int bo_ = ((tau) & 1) * 32768;                                                 \
    if constexpr (MODE == 0) {                                                     \
      const unsigned short* bp_ = w1tE +                                           \
          (size_t)(nbh8 + ((tau) >> 4)) * (256 * HH) + ((tau) & 15) * 64;          \
      gload_lds16(bp_ + oB##q##0, lds + lB + bo_ + (q) * 4096);                    \
      gload_lds16(bp_ + oB##q##1, lds + lB + bo_ + (q) * 4096 + 16384);            \
    } else {                                                                       \
      int kt_ = ((tau) < NTH) ? (tau) : (tau) - NTH;                               \
      const unsigned short* bp_ = (((tau) < NTH) ? B0p : B1p) + kt_ * 64;          \
      gload_lds16(bp_ + oB##q##0, lds + lB + bo_ + (q) * 4096);                    \
      gload_lds16(bp_ + oB##q##1, lds + lB + bo_ + (q) * 4096 + 16384);            \
    } } while (0)

#define STD8(T)                                                                    \
    PH1(0, { STAGE_A((T) + 1, 1); }, 0);                                           \
    PH2(0, { STAGE_B((T) + 1, 1); }, 0);                                           \
    PH3(0, { STAGE_A((T) + 2, 0); }, 0);                                           \
    PH4(0, { STAGE_B((T) + 2, 0); }, 4);                                           \
    PH1(1, { STAGE_A((T) + 2, 1); }, 0);                                           \
    PH2(1, { STAGE_B((T) + 2, 1); }, 0);                                           \
    PH3(1, { STAGE_A((T) + 3, 0); }, 0);                                           \
    PH4(1, { STAGE_B((T) + 3, 0); }, 4);

#define TAIL8(T)                                                                   \
    PH1(0, { STAGE_A((T) + 1, 1); }, 0);                                           \
    PH2(0, { STAGE_B((T) + 1, 1); }, 0);                                           \
    PH3(0, {}, 0);                                                                 \
    PH4(0, {}, 1);                                                                 \
    PH1(1, {}, 0);                                                                 \
    PH2(1, {}, 0);                                                                 \
    PH3(1, {}, 0);                                                                 \
    PH4(1, {}, 0);

template <int MODE>
__global__ __launch_bounds__(512, 1) void gemm8p(
    const unsigned short* __restrict__ XorH,   // MODE0: Xbf ; MODE1: hmid(permuted)
    const unsigned short* __restrict__ Wt,     // MODE0: w1t ; MODE1: w2t
    const float* __restrict__ bias,            // MODE0: pb1 ; MODE1: pb2
    const int* __restrict__ re,
    const float* __restrict__ rw,
    unsigned short* __restrict__ hmid_out,     // MODE0 out (permuted layout)
    float* __restrict__ out) {                 // MODE1 out
  extern __shared__ char lds[];

  constexpr int NT  = 128;                         // total K-tiles (both modes)
  constexpr int NTH = (MODE == 0) ? NT : (FF / 64);// MODE1: expert switch at 64

  int P = blockIdx.x;
  int t = threadIdx.x;
  int lane = t & 63, wv = t >> 6;
  int wr = wv >> 2, wc = wv & 3;       // 2M x 4N waves
  int ln = lane & 15, kq = lane >> 4;

  const unsigned short *A0p = nullptr, *w1tE = nullptr;
  const unsigned short *H0p = nullptr, *H1p = nullptr, *B0p = nullptr, *B1p = nullptr;
  int pair = 0, b, e0 = 0, e1 = 0, mb, nb = 0, nbh8 = 0;
  int ldb;
  if constexpr (MODE == 0) {
    b = P & 7;                       // XCD <-> batch
    int k = P >> 3;                  // 0..31 per batch
    int pairbit = k & 1;
    mb = (k >> 1) & 7;
    nbh8 = (k >> 4) * 8;             // nb-half base (0 or 8)
    pair = b * 2 + pairbit;
    e0 = re[pair];
    A0p = XorH + (size_t)b * TT * HH + (size_t)mb * 256 * HH;  // fixed all segments
    w1tE = Wt + (size_t)e0 * FF * HH;
    ldb = HH;
  } else {
    b = P & 7;                       // XCD <-> batch
    int idx = P >> 3;
    nb = idx & 3; mb = idx >> 2;
    e0 = re[2 * b]; e1 = re[2 * b + 1];
    H0p = XorH + (size_t)(2 * b) * TT * FF + (size_t)mb * 16 * 65536;
    H1p = H0p + (size_t)TT * FF;
    B0p = Wt + (size_t)e0 * FF * HH + (size_t)nb * 256 * FF;
    B1p = Wt + (size_t)e1 * FF * HH + (size_t)nb * 256 * FF;
    ldb = FF;
  }

  // -------- precomputed per-lane addressing (loop-invariant) --------
  int lrow = t >> 3;                          // A stage row lane part (0..63)
  int lrB8 = (t >> 8) * 64 + ((t >> 3) & 31); // B stage row lane part
  int clel = ((t & 7) ^ ((t >> 3) & 7)) * 8;  // inverse-swizzled col (elements)
  // MODE0 A offsets (row-major Xbf, lda=HH)
  size_t oA00 = (size_t)(lrow)*HH + clel;
  size_t oA01 = (size_t)(128 + lrow) * HH + clel;
  size_t oA10 = (size_t)(64 + lrow) * HH + clel;
  size_t oA11 = (size_t)(192 + lrow) * HH + clel;
  // MODE1 A offsets (permuted hmid): F(r) + clel terms
  int nnl = (clel >> 4) & 3, lnl = clel & 15;
#define FPERM(r) ((size_t)((((r) >> 7) & 1) * 32768 +                              \
                  ((((r) >> 4) & 7) * 16 + nnl * 4 + ((r) & 3)) * 64 +             \
                  (((r) >> 2) & 3) * 16 + lnl))
  size_t fA00 = FPERM(lrow);
  size_t fA01 = FPERM(128 + lrow);
  size_t fA10 = FPERM(64 + lrow);
  size_t fA11 = FPERM(192 + lrow);
#undef FPERM
  // B offsets (row-major Wt panels, ldb per mode)
  size_t oB00 = (size_t)(lrB8)*ldb + clel;
  size_t oB01 = (size_t)(128 + lrB8) * ldb + clel;
  size_t oB10 = (size_t)(32 + lrB8) * ldb + clel;
  size_t oB11 = (size_t)(160 + lrB8) * ldb + clel;
  // LDS stage dest lane bases (bytes)
  int lA = lrow * 128 + (t & 7) * 16;
  int lB = 65536 + lrB8 * 128 + (t & 7) * 16;
  // LDS read lane bases (bytes); row&7 == ln&7 for all fragment rows
  char* pA0 = lds + wr * 16384 + ln * 128 + ((kq ^ (ln & 7)) * 16);
  char* pA1 = lds + wr * 16384 + ln * 128 + (((4 + kq) ^ (ln & 7)) * 16);
  char* pB0 = lds + 65536 + wc * 8192 + ln * 128 + ((kq ^ (ln & 7)) * 16);
  char* pB1 = lds + 65536 + wc * 8192 + ln * 128 + (((4 + kq) ^ (ln & 7)) * 16);

  f32x4 acc[8][4];
#pragma unroll
  for (int m = 0; m < 8; m++)
#pragma unroll
    for (int n = 0; n < 4; n++) acc[m][n] = (f32x4){0.f, 0.f, 0.f, 0.f};

  sh8 Aq[8], B0r[4], B1r[4];

  // Prologue: tile0 fully (4 units), tile1 q0 (2 units). vmcnt(4)=2 units pending.
  STAGE_A(0, 0); STAGE_B(0, 0); STAGE_A(0, 1); STAGE_B(0, 1);
  STAGE_A(1, 0); STAGE_B(1, 0);
  asm volatile("s_waitcnt vmcnt(4)" ::: "memory");
  __builtin_amdgcn_sched_barrier(0);
  __builtin_amdgcn_s_barrier();

  if constexpr (MODE == 0) {
    float wgt = rw[pair];
    for (int seg = 0; seg < 8; ++seg) {
      int nIt = (seg == 7) ? 7 : 8;
      for (int it = 0; it < nIt; ++it) {
        int T = seg * 16 + it * 2;
        STD8(T);
      }
      if (seg == 7) { TAIL8(126); }
      // ----- segment epilogue: permuted-layout coalesced nt stores (no LDS) -----
      {
        int nbs = nbh8 + seg;
        float bbv[4];
#pragma unroll
        for (int nn = 0; nn < 4; nn++)
          bbv[nn] = bias[(size_t)e0 * FF + nbs * 256 + wc * 64 + nn * 16 + ln];
        unsigned short* Cp = hmid_out + (size_t)pair * TT * FF +
                             (size_t)(mb * 16 + nbs) * 65536 + wv * 8192 + lane;
#pragma unroll
        for (int mm = 0; mm < 8; mm++) {
#pragma unroll
          for (int nn = 0; nn < 4; nn++) {
#pragma unroll
            for (int j = 0; j < 4; j++) {
              float v = acc[mm][nn][j] + bbv[nn];
              float g = 0.5f * v * (1.0f + erf_fast(v * 0.70710678118654752f));
              __builtin_nontemporal_store(f2bf(wgt * g),
                                          Cp + (mm * 16 + nn * 4 + j) * 64);
            }
          }
        }
#pragma unroll
        for (int m = 0; m < 8; m++)
#pragma unroll
          for (int n = 0; n < 4; n++) acc[m][n] = (f32x4){0.f, 0.f, 0.f, 0.f};
      }
    }
  } else {
    for (int T = 0; T + 2 < NT; T += 2) {
      STD8(T);
    }
    TAIL8(NT - 2);
    // ----- epilogue: out = acc + weighted bias (nt stores, standard layout) -----
    float w0 = rw[2 * b], w1v = rw[2 * b + 1];
#pragma unroll
    for (int nn = 0; nn < 4; nn++) {
      int col = nb * 256 + wc * 64 + nn * 16 + ln;
      float bv = w0 * bias[(size_t)e0 * HH + col] + w1v * bias[(size_t)e1 * HH + col];
#pragma unroll
      for (int mm = 0; mm < 8; mm++) {
#pragma unroll
        for (int j = 0; j < 4; j++) {
          int row = mb * 256 + wr * 128 + mm * 16 + kq * 4 + j;
          __builtin_nontemporal_store(acc[mm][nn][j] + bv,
              &out[(size_t)b * TT * HH + (size_t)row * HH + col]);
        }
      }
    }
  }
}

extern "C" void kernel_launch(void* const* d_in, const int* in_sizes, int n_in,
                              void* d_out, int out_size, void* d_ws, size_t ws_size,
                              hipStream_t stream) {
  const float* X  = (const float*)d_in[0];
  const float* gw = (const float*)d_in[1];
  const float* w1 = (const float*)d_in[2];
  const float* pb1 = (const float*)d_in[3];
  const float* w2 = (const float*)d_in[4];
  const float* pb2 = (const float*)d_in[5];
  float* out = (float*)d_out;

  char* ws = (char*)d_ws;
  int* re = (int*)ws;                     // 16 ints
  float* rw = (float*)(ws + 64);          // 16 floats
  float* partial = (float*)(ws + 256);    // [B][16][H] f32 = 512KB
  unsigned short* Xbf = (unsigned short*)(ws + 256 + 524288);  // [B][T][H] bf16 = 32MB
  const size_t fixed = 256 + 524288 + (size_t)BB * TT * HH * 2;

  unsigned short* w1t = (unsigned short*)(ws + fixed);                          // 64MB
  unsigned short* w2t = (unsigned short*)(ws + fixed + (size_t)EE * HH * FF * 2);
  unsigned short* hmid = (unsigned short*)(ws + fixed + (size_t)2 * EE * HH * FF * 2); // 256MB

  hipFuncSetAttribute((const void*)gemm8p<0>,
                      hipFuncAttributeMaxDynamicSharedMemorySize, 131072);
  hipFuncSetAttribute((const void*)gemm8p<1>,
                      hipFuncAttributeMaxDynamicSharedMemorySize, 131072);

  prep<<<dim3(16, BB), 256, 0, stream>>>(X, Xbf, partial);
  gating_kernel<<<BB, 256, 0, stream>>>(partial, gw, re, rw);

  transposeE<<<dim3(HH / 64, FF / 64, EE), 256, 0, stream>>>(w1, w1t, re, HH, FF);
  transposeE<<<dim3(FF / 64, HH / 64, EE), 256, 0, stream>>>(w2, w2t, re, FF, HH);

  gemm8p<0><<<256, 512, 131072, stream>>>(Xbf, w1t, pb1, re, rw, hmid, nullptr);
  gemm8p<1><<<256, 512, 131072, stream>>>(hmid, w2t, pb2, re, rw, nullptr, out);
}